// Round 2
// baseline (1024.443 us; speedup 1.0000x reference)
//
#include <hip/hip_runtime.h>

#define B_ 4
#define S_ 4096
#define D_ 1024
#define H_ 16
#define DH 64
#define CHUNK 64
#define NC (S_ / CHUNK)   // 64 chunks
#define BH (B_ * H_)      // 64 (b,h) sequences
#define STATE_N 4160      // 64*64 S entries + 64 z entries
#define EPS 1e-6f

typedef __bf16 bf16;
typedef __bf16 bf16x8 __attribute__((ext_vector_type(8)));
typedef __bf16 bf16x4 __attribute__((ext_vector_type(4)));
typedef float v4f __attribute__((ext_vector_type(4)));

#define MFMA16(a, b, c) __builtin_amdgcn_mfma_f32_16x16x32_bf16(a, b, c, 0, 0, 0)

// async global->LDS, 16B per lane; LDS dest = wave-uniform base + lane*16
__device__ __forceinline__ void load_lds16(const bf16* g, bf16* l) {
  __builtin_amdgcn_global_load_lds(
      (const __attribute__((address_space(1))) unsigned int*)g,
      (__attribute__((address_space(3))) unsigned int*)l, 16, 0, 0);
}

// ---------------------------------------------------------------------------
// fp32 -> bf16 convert (x): 8 elems/thread, vectorized.
// ---------------------------------------------------------------------------
__global__ __launch_bounds__(256) void cvt_f32_bf16(const float* __restrict__ in,
                                                    bf16* __restrict__ out) {
  const size_t i = ((size_t)blockIdx.x * 256 + threadIdx.x) * 8;
  float4 a = *(const float4*)(in + i);
  float4 b = *(const float4*)(in + i + 4);
  bf16x8 o;
  o[0] = (bf16)a.x; o[1] = (bf16)a.y; o[2] = (bf16)a.z; o[3] = (bf16)a.w;
  o[4] = (bf16)b.x; o[5] = (bf16)b.y; o[6] = (bf16)b.z; o[7] = (bf16)b.w;
  *(bf16x8*)(out + i) = o;
}

// ---------------------------------------------------------------------------
// Fused weight transpose + fp32->bf16 for all 4 weights (z selects matrix).
// ---------------------------------------------------------------------------
__global__ __launch_bounds__(256) void transpose_w4(
    const float* __restrict__ w0, const float* __restrict__ w1,
    const float* __restrict__ w2, const float* __restrict__ w3,
    bf16* __restrict__ out) {
  __shared__ float tile[32][33];
  const int z = blockIdx.z;
  const float* in = (z == 0) ? w0 : (z == 1) ? w1 : (z == 2) ? w2 : w3;
  bf16* o = out + (size_t)z * D_ * D_;
  const int bx = blockIdx.x * 32, by = blockIdx.y * 32;
  const int tx = threadIdx.x & 31, ty = threadIdx.x >> 5;  // 32 x 8
#pragma unroll
  for (int i = 0; i < 32; i += 8)
    tile[ty + i][tx] = in[(size_t)(by + ty + i) * D_ + bx + tx];
  __syncthreads();
#pragma unroll
  for (int i = 0; i < 32; i += 8)
    o[(size_t)(bx + ty + i) * D_ + by + tx] = (bf16)tile[tx][ty + i];
}

// ---------------------------------------------------------------------------
// 256x256 8-phase NT GEMM (m201-style schedule in plain HIP).
// BK=64, 8 waves (2M x 4N), LDS 128KB double-buffered, global_load_lds x16B.
// __launch_bounds__(512, 1): LDS already caps at 1 block/CU (2 waves/SIMD);
// a tighter bound forces a 128-reg cap -> ~100 spilled regs -> 1.1 GB of
// scratch traffic (measured round 1). Do NOT tighten this.
// Counted vmcnt: steady 4/4/-/4 per tile, epilogue drains 2 -> 0.
// ---------------------------------------------------------------------------
#define PHASE(S, MH, NH, LA, LB, STMT, WN)                                     \
  do {                                                                         \
    if (LA) {                                                                  \
      _Pragma("unroll") for (int m = 0; m < 4; m++) {                          \
        aR[m][0] = *(const bf16x8*)&lds[(S)*16384 + (MH)*8192 + m*512 + aoff]; \
        aR[m][1] = *(const bf16x8*)&lds[(S)*16384 + (MH)*8192 + 4096 + m*512 + aoff]; \
      }                                                                        \
    }                                                                          \
    if (LB) {                                                                  \
      _Pragma("unroll") for (int n = 0; n < 2; n++) {                          \
        bR[NH][n][0] = *(const bf16x8*)&lds[(S)*16384 + (NH)*8192 + n*512 + boff]; \
        bR[NH][n][1] = *(const bf16x8*)&lds[(S)*16384 + (NH)*8192 + 4096 + n*512 + boff]; \
      }                                                                        \
    }                                                                          \
    STMT;                                                                      \
    if ((WN) == 4) asm volatile("s_waitcnt vmcnt(4)" ::: "memory");            \
    else if ((WN) == 2) asm volatile("s_waitcnt vmcnt(2)" ::: "memory");       \
    else if ((WN) == 0) asm volatile("s_waitcnt vmcnt(0)" ::: "memory");       \
    __builtin_amdgcn_s_barrier();                                              \
    __builtin_amdgcn_s_setprio(1);                                             \
    _Pragma("unroll") for (int ks = 0; ks < 2; ks++)                           \
      _Pragma("unroll") for (int m = 0; m < 4; m++)                            \
        _Pragma("unroll") for (int n = 0; n < 2; n++)                          \
          acc[MH][m][NH][n] = MFMA16(aR[m][ks], bR[NH][n][ks], acc[MH][m][NH][n]); \
    __builtin_amdgcn_s_setprio(0);                                             \
    __builtin_amdgcn_s_barrier();                                              \
  } while (0)

__global__ __launch_bounds__(512, 1) void gemm256(const bf16* __restrict__ A,
                                                  const bf16* __restrict__ BT,
                                                  bf16* __restrict__ o0,
                                                  bf16* __restrict__ o1,
                                                  bf16* __restrict__ o2,
                                                  float* __restrict__ of) {
  __shared__ __align__(16) bf16 lds[65536];  // A at 0 (64KB), B at 32768 (64KB)
  const int tid = threadIdx.x;
  const int wv = tid >> 6, lane = tid & 63;
  const int quad = lane >> 4, l16 = lane & 15;
  const int wr = wv >> 2, wc = wv & 3;  // 2 x 4 wave grid
  const int bm = blockIdx.x * 256;
  const int by = blockIdx.y;
  const int zz = of ? 0 : (by >> 2);
  const int colg = of ? by * 256 : (by & 3) * 256;
  const int act = (of == nullptr) && (zz < 2);
  bf16* ob = (zz == 0) ? o0 : (zz == 1) ? o1 : o2;

  // ---- staging source pointers (per-lane, inverse-swizzled group) ----
  const int r = tid >> 2;                      // 0..127: row within half
  const int gsw = (tid & 3) ^ ((r >> 2) & 3);  // swizzled 8-elem group
  const bf16* sA0 = A + (size_t)(bm + r) * D_ + gsw * 8;
  const bf16* sA1 = A + (size_t)(bm + 128 + r) * D_ + gsw * 8;
  const bf16* sB0 = BT + ((size_t)by * 256 + r) * D_ + gsw * 8;
  const bf16* sB1 = BT + ((size_t)by * 256 + 128 + r) * D_ + gsw * 8;

  auto stageA = [&](int h, int kt, int s) {
    const bf16* src = (h ? sA1 : sA0) + kt * 64;
    bf16* d = &lds[s * 16384 + h * 8192 + wv * 512];  // wave-uniform base
    load_lds16(src, d);              // ks0
    load_lds16(src + 32, d + 4096);  // ks1
  };
  auto stageB = [&](int h, int kt, int s) {
    const bf16* src = (h ? sB1 : sB0) + kt * 64;
    bf16* d = &lds[32768 + s * 16384 + h * 8192 + wv * 512];
    load_lds16(src, d);
    load_lds16(src + 32, d + 4096);
  };

  // ---- read-side offsets (elements), swizzled ----
  const int qsw = quad ^ ((l16 >> 2) & 3);
  const int aoff = (wr * 64 + l16) * 32 + qsw * 8;
  const int boff = 32768 + (wc * 32 + l16) * 32 + qsw * 8;

  v4f acc[2][4][2][2];
#pragma unroll
  for (int a0 = 0; a0 < 2; a0++)
#pragma unroll
    for (int a1 = 0; a1 < 4; a1++)
#pragma unroll
      for (int a2 = 0; a2 < 2; a2++)
#pragma unroll
        for (int a3 = 0; a3 < 2; a3++) acc[a0][a1][a2][a3] = (v4f){0.f, 0.f, 0.f, 0.f};
  bf16x8 aR[4][2];
  bf16x8 bR[2][2][2];

  // ---- prologue: stage tile 0 into s=0, issue order A0,B0,B1,A1 ----
  stageA(0, 0, 0); stageB(0, 0, 0); stageB(1, 0, 0); stageA(1, 0, 0);
  asm volatile("s_waitcnt vmcnt(4)" ::: "memory");  // A0,B0 landed
  __builtin_amdgcn_s_barrier();

  constexpr int NK = D_ / 64;  // 16 K-tiles
#pragma unroll 1
  for (int t = 0; t < NK; t += 2) {
    // tile t (s=0): stage t+1 -> s=1  (t+1 <= 15 always)
    PHASE(0, 0, 0, 1, 1, stageA(0, t + 1, 1), 4);
    PHASE(0, 0, 1, 0, 1, stageB(0, t + 1, 1), 4);
    PHASE(0, 1, 1, 1, 0, stageB(1, t + 1, 1), -1);
    PHASE(0, 1, 0, 0, 0, stageA(1, t + 1, 1), 4);
    if (t + 2 < NK) {
      // tile t+1 (s=1): stage t+2 -> s=0
      PHASE(1, 0, 0, 1, 1, stageA(0, t + 2, 0), 4);
      PHASE(1, 0, 1, 0, 1, stageB(0, t + 2, 0), 4);
      PHASE(1, 1, 1, 1, 0, stageB(1, t + 2, 0), -1);
      PHASE(1, 1, 0, 0, 0, stageA(1, t + 2, 0), 4);
    } else {
      // last tile: epilogue drain 2 -> 0
      PHASE(1, 0, 0, 1, 1, (void)0, 2);
      PHASE(1, 0, 1, 0, 1, (void)0, 0);
      PHASE(1, 1, 1, 1, 0, (void)0, -1);
      PHASE(1, 1, 0, 0, 0, (void)0, -1);
    }
  }

  // ---- coalesced epilogue through LDS (reuse), stride 260 f32 ----
  __syncthreads();
  float* Cl = (float*)lds;  // [2 wr][32 rows][260]
  const int erow = tid >> 3;            // 0..63
  const int wrr = erow >> 5, mrow = erow & 31;
  const int rot = tid & 7;              // per-lane chunk rotation (bank spread)
  const int seg = (tid & 7) * 32;       // f32 segment
#pragma unroll
  for (int i = 0; i < 4; i++) {
    const int mh = i >> 1, mp = i & 1;
#pragma unroll
    for (int mm = 0; mm < 2; mm++) {
      const int m = mp * 2 + mm;
#pragma unroll
      for (int nh = 0; nh < 2; nh++)
#pragma unroll
        for (int n = 0; n < 2; n++)
#pragma unroll
          for (int rr = 0; rr < 4; rr++) {
            float x = acc[mh][m][nh][n][rr];
            if (act) x = x > 0.f ? x + 1.f : __expf(x);
            Cl[(wr * 32 + mm * 16 + quad * 4 + rr) * 260 +
               nh * 128 + wc * 32 + n * 16 + l16] = x;
          }
    }
    __syncthreads();
    const float* srcp = &Cl[(wrr * 32 + mrow) * 260 + seg];
    const size_t grow = (size_t)(bm + mh * 128 + wrr * 64 + mp * 32 + mrow);
    if (of) {
      float* dst = of + grow * D_ + colg + seg;
#pragma unroll
      for (int u = 0; u < 8; u++) {
        const int uu = (u + rot) & 7;  // rotate: 8 same-row lanes hit 8 bank-quads
        *(float4*)(dst + uu * 4) = *(const float4*)(srcp + uu * 4);
      }
    } else {
      bf16* dst = ob + grow * D_ + colg + seg;
#pragma unroll
      for (int u = 0; u < 4; u++) {
        const int uu = (u + rot) & 3;
        bf16x8 q;
#pragma unroll
        for (int e = 0; e < 8; e++) q[e] = (bf16)srcp[uu * 8 + e];
        *(bf16x8*)(dst + uu * 8) = q;
      }
    }
    __syncthreads();
  }
}

// ---------------------------------------------------------------------------
// Pass 1: per-chunk KV outer-product sums + k-sums (fp32).
// ---------------------------------------------------------------------------
__global__ __launch_bounds__(256) void chunk_kv(const bf16* __restrict__ kb,
                                                const bf16* __restrict__ vb,
                                                float* __restrict__ states) {
  constexpr int LD = 88;
  __shared__ bf16 Kl[CHUNK * LD];
  __shared__ bf16 Vl[CHUNK * LD];
  const int tid = threadIdx.x;
  const int c = blockIdx.x, bh = blockIdx.y;
  const int b = bh >> 4, h = bh & 15;
  const size_t gbase = ((size_t)(b * S_ + c * CHUNK)) * D_ + h * DH;
#pragma unroll
  for (int rep = 0; rep < 2; rep++) {
    int flat = tid + rep * 256;
    int rr = flat >> 3, sg = (flat & 7) * 8;
    *(bf16x8*)&Kl[rr * LD + sg] = *(const bf16x8*)(kb + gbase + (size_t)rr * D_ + sg);
    *(bf16x8*)&Vl[rr * LD + sg] = *(const bf16x8*)(vb + gbase + (size_t)rr * D_ + sg);
  }
  __syncthreads();
  const int d0 = (tid >> 4) * 4, e0 = (tid & 15) * 4;
  float acc[4][4] = {};
  for (int t = 0; t < CHUNK; t++) {
    bf16x4 k4 = *(const bf16x4*)&Kl[t * LD + d0];
    bf16x4 v4 = *(const bf16x4*)&Vl[t * LD + e0];
    float kf[4], vf[4];
#pragma unroll
    for (int i = 0; i < 4; i++) { kf[i] = (float)k4[i]; vf[i] = (float)v4[i]; }
#pragma unroll
    for (int i = 0; i < 4; i++)
#pragma unroll
      for (int j = 0; j < 4; j++) acc[i][j] += kf[i] * vf[j];
  }
  float* out = states + ((size_t)bh * NC + c) * STATE_N;
#pragma unroll
  for (int i = 0; i < 4; i++)
#pragma unroll
    for (int j = 0; j < 4; j++) out[(d0 + i) * 64 + (e0 + j)] = acc[i][j];
  if (tid < 64) {
    float zs = 0.f;
    for (int t = 0; t < CHUNK; t++) zs += (float)Kl[t * LD + tid];
    out[4096 + tid] = zs;
  }
}

// ---------------------------------------------------------------------------
// Exclusive prefix over chunks + state_cache init (fp32 input).
// ---------------------------------------------------------------------------
__global__ __launch_bounds__(256) void state_prefix(const float* __restrict__ sc,
                                                    float* __restrict__ states) {
  const int bh = blockIdx.x;
  const int e = blockIdx.y * 256 + threadIdx.x;
  if (e >= STATE_N) return;
  const float* scb = sc + (size_t)bh * (DH + 1) * DH;
  float run = scb[e];
  float* p = states + (size_t)bh * NC * STATE_N + e;
  for (int c = 0; c < NC; c++) {
    float tmp = p[(size_t)c * STATE_N];
    p[(size_t)c * STATE_N] = run;
    run += tmp;
  }
}

// ---------------------------------------------------------------------------
// Pass 2: P = mask(Q K^T), num = P@V + Q@S0, den = rowsum(P) + Q.z0.
// ---------------------------------------------------------------------------
__global__ __launch_bounds__(256) void attn_pass2(
    const bf16* __restrict__ qb, const bf16* __restrict__ kb,
    const bf16* __restrict__ vb, const float* __restrict__ states,
    bf16* __restrict__ ao) {
  constexpr int LD = 88;
  __shared__ bf16 Ql[CHUNK * LD];
  __shared__ bf16 Kl[CHUNK * LD];
  __shared__ bf16 VT[DH * LD];
  __shared__ bf16 S0T[DH * LD];
  __shared__ bf16 Pl[CHUNK * LD];
  __shared__ float denl[CHUNK];
  __shared__ float z0l[DH];
  const int tid = threadIdx.x;
  const int wave = tid >> 6, lane = tid & 63;
  const int quad = lane >> 4, l16 = lane & 15;
  const int c = blockIdx.x, bh = blockIdx.y;
  const int b = bh >> 4, h = bh & 15;
  const size_t gbase = ((size_t)(b * S_ + c * CHUNK)) * D_ + h * DH;

#pragma unroll
  for (int rep = 0; rep < 2; rep++) {
    int flat = tid + rep * 256;
    int rr = flat >> 3, sg = (flat & 7) * 8;
    *(bf16x8*)&Ql[rr * LD + sg] = *(const bf16x8*)(qb + gbase + (size_t)rr * D_ + sg);
    *(bf16x8*)&Kl[rr * LD + sg] = *(const bf16x8*)(kb + gbase + (size_t)rr * D_ + sg);
    bf16x8 vv = *(const bf16x8*)(vb + gbase + (size_t)rr * D_ + sg);
#pragma unroll
    for (int u = 0; u < 8; u++) VT[(sg + u) * LD + rr] = vv[u];
  }
  const float* st = states + ((size_t)bh * NC + c) * STATE_N;
  for (int f = tid; f < 4096; f += 256) S0T[(f & 63) * LD + (f >> 6)] = (bf16)st[f];
  if (tid < DH) z0l[tid] = st[4096 + tid];
  __syncthreads();

  v4f zero = {0.f, 0.f, 0.f, 0.f};
  v4f pacc[4];
#pragma unroll
  for (int j = 0; j < 4; j++) pacc[j] = zero;
#pragma unroll
  for (int ks = 0; ks < 2; ks++) {
    bf16x8 aq = *(const bf16x8*)&Ql[(wave * 16 + l16) * LD + ks * 32 + quad * 8];
#pragma unroll
    for (int j = 0; j < 4; j++) {
      bf16x8 bk = *(const bf16x8*)&Kl[(j * 16 + l16) * LD + ks * 32 + quad * 8];
      pacc[j] = MFMA16(aq, bk, pacc[j]);
    }
  }
  float rs[4] = {0.f, 0.f, 0.f, 0.f};
#pragma unroll
  for (int j = 0; j < 4; j++) {
#pragma unroll
    for (int rr = 0; rr < 4; rr++) {
      int t = wave * 16 + quad * 4 + rr;
      int col = j * 16 + l16;
      float p = (col <= t) ? pacc[j][rr] : 0.f;
      Pl[t * LD + col] = (bf16)p;
      rs[rr] += p;
    }
  }
#pragma unroll
  for (int m = 1; m < 16; m <<= 1)
#pragma unroll
    for (int rr = 0; rr < 4; rr++) rs[rr] += __shfl_xor(rs[rr], m, 64);
  if (l16 == 0)
#pragma unroll
    for (int rr = 0; rr < 4; rr++) denl[wave * 16 + quad * 4 + rr] = rs[rr];
  __syncthreads();
  if (tid < CHUNK) {
    float qz = 0.f;
    for (int d = 0; d < DH; d++) qz += (float)Ql[tid * LD + d] * z0l[d];
    denl[tid] += qz;
  }
  __syncthreads();

  v4f nacc[4];
#pragma unroll
  for (int j = 0; j < 4; j++) nacc[j] = zero;
#pragma unroll
  for (int ks = 0; ks < 2; ks++) {
    bf16x8 ap = *(const bf16x8*)&Pl[(wave * 16 + l16) * LD + ks * 32 + quad * 8];
#pragma unroll
    for (int j = 0; j < 4; j++) {
      bf16x8 bv = *(const bf16x8*)&VT[(j * 16 + l16) * LD + ks * 32 + quad * 8];
      nacc[j] = MFMA16(ap, bv, nacc[j]);
    }
  }
#pragma unroll
  for (int ks = 0; ks < 2; ks++) {
    bf16x8 aq = *(const bf16x8*)&Ql[(wave * 16 + l16) * LD + ks * 32 + quad * 8];
#pragma unroll
    for (int j = 0; j < 4; j++) {
      bf16x8 bs = *(const bf16x8*)&S0T[(j * 16 + l16) * LD + ks * 32 + quad * 8];
      nacc[j] = MFMA16(aq, bs, nacc[j]);
    }
  }
#pragma unroll
  for (int j = 0; j < 4; j++) {
#pragma unroll
    for (int rr = 0; rr < 4; rr++) {
      int t = wave * 16 + quad * 4 + rr;
      int e = j * 16 + l16;
      float o = nacc[j][rr] / (denl[t] + EPS);
      ao[gbase + (size_t)t * D_ + e] = (bf16)o;
    }
  }
}

// ---------------------------------------------------------------------------
extern "C" void kernel_launch(void* const* d_in, const int* in_sizes, int n_in,
                              void* d_out, int out_size, void* d_ws, size_t ws_size,
                              hipStream_t stream) {
  const float* x  = (const float*)d_in[0];
  const float* sc = (const float*)d_in[1];
  const float* Wq = (const float*)d_in[2];
  const float* Wk = (const float*)d_in[3];
  const float* Wv = (const float*)d_in[4];
  const float* Wo = (const float*)d_in[5];
  float* out = (float*)d_out;

  const size_t MSZ = (size_t)B_ * S_ * D_;  // 16,777,216 elems
  const size_t WSZ = (size_t)D_ * D_;       // 1,048,576 elems
  bf16* xb = (bf16*)d_ws;
  bf16* qb = xb + MSZ;
  bf16* kb = qb + MSZ;
  bf16* vb = kb + MSZ;
  bf16* ao = vb + MSZ;
  bf16* wt = ao + MSZ;  // 4 transposed bf16 weight matrices [q|k|v|o]
  float* states = (float*)(wt + 4 * WSZ);  // BH*NC*4160 fp32 (~68 MB)

  cvt_f32_bf16<<<MSZ / (256 * 8), 256, 0, stream>>>(x, xb);
  transpose_w4<<<dim3(32, 32, 4), 256, 0, stream>>>(Wq, Wk, Wv, Wo, wt);

  // fused QKV GEMM: BT rows 0..3071 span wt[q|k|v]; 256x256 tiles
  gemm256<<<dim3(64, 12), 512, 0, stream>>>(xb, wt, qb, kb, vb, nullptr);

  chunk_kv<<<dim3(NC, BH), 256, 0, stream>>>(kb, vb, states);
  state_prefix<<<dim3(BH, 17), 256, 0, stream>>>(sc, states);
  attn_pass2<<<dim3(NC, BH), 256, 0, stream>>>(qb, kb, vb, states, ao);

  gemm256<<<dim3(64, 4), 512, 0, stream>>>(ao, wt + 3 * WSZ, nullptr, nullptr,
                                           nullptr, out);
}

// Round 3
// 419.433 us; speedup vs baseline: 2.4424x; 2.4424x over previous
//
#include <hip/hip_runtime.h>

#define B_ 4
#define S_ 4096
#define D_ 1024
#define H_ 16
#define DH 64
#define CHUNK 64
#define NC (S_ / CHUNK)   // 64 chunks
#define BH (B_ * H_)      // 64 (b,h) sequences
#define STATE_N 4160      // 64*64 S entries + 64 z entries
#define EPS 1e-6f

typedef __bf16 bf16;
typedef __bf16 bf16x8 __attribute__((ext_vector_type(8)));
typedef __bf16 bf16x4 __attribute__((ext_vector_type(4)));
typedef float v4f __attribute__((ext_vector_type(4)));

#define MFMA16(a, b, c) __builtin_amdgcn_mfma_f32_16x16x32_bf16(a, b, c, 0, 0, 0)

// async global->LDS, 16B per lane; LDS dest = wave-uniform base + lane*16
__device__ __forceinline__ void load_lds16(const bf16* g, bf16* l) {
  __builtin_amdgcn_global_load_lds(
      (const __attribute__((address_space(1))) unsigned int*)g,
      (__attribute__((address_space(3))) unsigned int*)l, 16, 0, 0);
}

// ---------------------------------------------------------------------------
// fp32 -> bf16 convert (x): 8 elems/thread, vectorized.
// ---------------------------------------------------------------------------
__global__ __launch_bounds__(256) void cvt_f32_bf16(const float* __restrict__ in,
                                                    bf16* __restrict__ out) {
  const size_t i = ((size_t)blockIdx.x * 256 + threadIdx.x) * 8;
  float4 a = *(const float4*)(in + i);
  float4 b = *(const float4*)(in + i + 4);
  bf16x8 o;
  o[0] = (bf16)a.x; o[1] = (bf16)a.y; o[2] = (bf16)a.z; o[3] = (bf16)a.w;
  o[4] = (bf16)b.x; o[5] = (bf16)b.y; o[6] = (bf16)b.z; o[7] = (bf16)b.w;
  *(bf16x8*)(out + i) = o;
}

// ---------------------------------------------------------------------------
// Fused weight transpose + fp32->bf16 for all 4 weights (z selects matrix).
// out[z][n*1024+k] = (bf16)W_z[k*1024+n]
// ---------------------------------------------------------------------------
__global__ __launch_bounds__(256) void transpose_w4(
    const float* __restrict__ w0, const float* __restrict__ w1,
    const float* __restrict__ w2, const float* __restrict__ w3,
    bf16* __restrict__ out) {
  __shared__ float tile[32][33];
  const int z = blockIdx.z;
  const float* in = (z == 0) ? w0 : (z == 1) ? w1 : (z == 2) ? w2 : w3;
  bf16* o = out + (size_t)z * D_ * D_;
  const int bx = blockIdx.x * 32, by = blockIdx.y * 32;
  const int tx = threadIdx.x & 31, ty = threadIdx.x >> 5;  // 32 x 8
#pragma unroll
  for (int i = 0; i < 32; i += 8)
    tile[ty + i][tx] = in[(size_t)(by + ty + i) * D_ + bx + tx];
  __syncthreads();
#pragma unroll
  for (int i = 0; i < 32; i += 8)
    o[(size_t)(bx + ty + i) * D_ + by + tx] = (bf16)tile[tx][ty + i];
}

// ---------------------------------------------------------------------------
// NT GEMM, double-buffered global_load_lds prefetch, SWIZZLED LDS staging.
// (Round-0 proven kernel: 142 us QKV, 84 VGPR, no spill. The 256x256 8-phase
// variant spilled ~1.1 GB of scratch to HBM on this compiler — do not retry
// without allocator evidence.)
// ---------------------------------------------------------------------------
__global__ __launch_bounds__(256) void gemm_nt(const bf16* __restrict__ A,
                                               const bf16* __restrict__ BT,
                                               bf16* __restrict__ o0,
                                               bf16* __restrict__ o1,
                                               bf16* __restrict__ o2,
                                               float* __restrict__ of) {
  constexpr int TM = 128, BK = 32;
  constexpr int CLD = 132;  // epilogue fp32 row stride
  __shared__ __align__(16) char smem[32768];  // 2 x (A 8KB + B 8KB); epilogue reuse
  float* Cl = (float*)smem;  // [32][132] fp32 (16896B)

  const int tid = threadIdx.x;
  const int wave = tid >> 6, lane = tid & 63;
  const int quad = lane >> 4, l16 = lane & 15;
  const int bm = blockIdx.x * TM;
  const int zz = blockIdx.y >> 3;
  const int colg = (blockIdx.y & 7) * 128;  // global col base of this tile
  const int wm = (wave & 1) * 64, wn = (wave >> 1) * 64;
  const int act = (of == nullptr) && (zz < 2);
  bf16* ob = (zz == 0) ? o0 : (zz == 1) ? o1 : o2;

  // staging: lane -> row wave*16 + lane/4 (+64 for 2nd call), swizzled group
  const int srow = wave * 16 + (lane >> 2);
  const int sgrp = ((lane & 3) - ((lane >> 2) >> 1)) & 3;  // swizzle
  const bf16* gA0 = A + (size_t)(bm + srow) * D_ + sgrp * 8;
  const bf16* gA1 = gA0 + (size_t)64 * D_;
  const bf16* gB0 = BT + ((size_t)blockIdx.y * 128 + srow) * D_ + sgrp * 8;
  const bf16* gB1 = gB0 + (size_t)64 * D_;

  // read-side swizzled (loop-invariant) fragment offsets
  int offA[4], offB[4];
#pragma unroll
  for (int i = 0; i < 4; i++) {
    const int pg = (quad + (l16 >> 1)) & 3;  // swizzled group
    offA[i] = (wm + i * 16 + l16) * BK + pg * 8;
    offB[i] = (wn + i * 16 + l16) * BK + pg * 8;
  }

  v4f zero = {0.f, 0.f, 0.f, 0.f};
  v4f acc[4][4];
#pragma unroll
  for (int i = 0; i < 4; i++)
#pragma unroll
    for (int j = 0; j < 4; j++) acc[i][j] = zero;

  auto stage = [&](int ks, int s) {
    bf16* As = (bf16*)(smem + s * 16384);
    bf16* Bs = As + 4096;
    const int ko = ks * BK;
    load_lds16(gA0 + ko, As + wave * 16 * BK);
    load_lds16(gA1 + ko, As + (64 + wave * 16) * BK);
    load_lds16(gB0 + ko, Bs + wave * 16 * BK);
    load_lds16(gB1 + ko, Bs + (64 + wave * 16) * BK);
  };
  auto compute = [&](int s) {
    const bf16* As = (const bf16*)(smem + s * 16384);
    const bf16* Bs = As + 4096;
    bf16x8 af[4], bfr[4];
#pragma unroll
    for (int i = 0; i < 4; i++) af[i] = *(const bf16x8*)&As[offA[i]];
#pragma unroll
    for (int j = 0; j < 4; j++) bfr[j] = *(const bf16x8*)&Bs[offB[j]];
#pragma unroll
    for (int i = 0; i < 4; i++)
#pragma unroll
      for (int j = 0; j < 4; j++) acc[i][j] = MFMA16(af[i], bfr[j], acc[i][j]);
  };

  constexpr int NK = D_ / BK;  // 32
  stage(0, 0);
  __syncthreads();  // slot 0 staged
  for (int k = 0; k < NK; k += 2) {
    if (k + 1 < NK) stage(k + 1, 1);  // in flight during compute(0)
    compute(0);
    __syncthreads();  // drains k+1 loads; slot-0 reads done
    if (k + 2 < NK) stage(k + 2, 0);
    compute(1);
    __syncthreads();
  }

  // ---- coalesced epilogue through LDS ----
  const int lr = (wave & 1) * 16 + quad * 4;
  const int rrow = tid >> 3;
  const int rseg = (tid & 7) * 16;
  const int grow = bm + (rrow >> 4) * 64 + (rrow & 15);
#pragma unroll
  for (int i = 0; i < 4; i++) {
    __syncthreads();
#pragma unroll
    for (int j = 0; j < 4; j++) {
      const int col = wn + j * 16 + l16;
#pragma unroll
      for (int r = 0; r < 4; r++) {
        float x = acc[i][j][r];
        if (act) x = x > 0.f ? x + 1.f : __expf(x);
        Cl[(lr + r) * CLD + col] = x;
      }
    }
    __syncthreads();
    const float* src = &Cl[rrow * CLD + rseg];
    if (of) {
      float* dst = of + (size_t)(grow + i * 16) * D_ + colg + rseg;
#pragma unroll
      for (int u = 0; u < 4; u++)
        *(float4*)(dst + u * 4) = *(const float4*)(src + u * 4);
    } else {
      bf16x8 q0, q1;
#pragma unroll
      for (int u = 0; u < 8; u++) { q0[u] = (bf16)src[u]; q1[u] = (bf16)src[8 + u]; }
      bf16* dst = ob + (size_t)(grow + i * 16) * D_ + colg + rseg;
      *(bf16x8*)dst = q0;
      *(bf16x8*)(dst + 8) = q1;
    }
  }
}

// ---------------------------------------------------------------------------
// Pass 1: per-chunk KV outer-product sums + k-sums (fp32).
// grid (NC, BH).  states[bh][c][d*64+e] = sum_t k[t][d]*v[t][e];  [4096+d]=sum k
// ---------------------------------------------------------------------------
__global__ __launch_bounds__(256) void chunk_kv(const bf16* __restrict__ kb,
                                                const bf16* __restrict__ vb,
                                                float* __restrict__ states) {
  constexpr int LD = 88;
  __shared__ bf16 Kl[CHUNK * LD];
  __shared__ bf16 Vl[CHUNK * LD];
  const int tid = threadIdx.x;
  const int c = blockIdx.x, bh = blockIdx.y;
  const int b = bh >> 4, h = bh & 15;
  const size_t gbase = ((size_t)(b * S_ + c * CHUNK)) * D_ + h * DH;
#pragma unroll
  for (int rep = 0; rep < 2; rep++) {
    int flat = tid + rep * 256;
    int r = flat >> 3, sg = (flat & 7) * 8;
    *(bf16x8*)&Kl[r * LD + sg] = *(const bf16x8*)(kb + gbase + (size_t)r * D_ + sg);
    *(bf16x8*)&Vl[r * LD + sg] = *(const bf16x8*)(vb + gbase + (size_t)r * D_ + sg);
  }
  __syncthreads();
  const int d0 = (tid >> 4) * 4, e0 = (tid & 15) * 4;
  float acc[4][4] = {};
  for (int t = 0; t < CHUNK; t++) {
    bf16x4 k4 = *(const bf16x4*)&Kl[t * LD + d0];
    bf16x4 v4 = *(const bf16x4*)&Vl[t * LD + e0];
    float kf[4], vf[4];
#pragma unroll
    for (int i = 0; i < 4; i++) { kf[i] = (float)k4[i]; vf[i] = (float)v4[i]; }
#pragma unroll
    for (int i = 0; i < 4; i++)
#pragma unroll
      for (int j = 0; j < 4; j++) acc[i][j] += kf[i] * vf[j];
  }
  float* out = states + ((size_t)bh * NC + c) * STATE_N;
#pragma unroll
  for (int i = 0; i < 4; i++)
#pragma unroll
    for (int j = 0; j < 4; j++) out[(d0 + i) * 64 + (e0 + j)] = acc[i][j];
  if (tid < 64) {
    float zs = 0.f;
    for (int t = 0; t < CHUNK; t++) zs += (float)Kl[t * LD + tid];
    out[4096 + tid] = zs;
  }
}

// ---------------------------------------------------------------------------
// Exclusive prefix over chunks + state_cache init (fp32 carry).
// S-part (e<4096): emit bf16 exclusive-prefix into stb (attn_pass2 rounds to
// bf16 anyway — numerics identical to baseline).  z-part (e>=4096): fp32 in
// place.  grid (BH, 17) x 256.
// ---------------------------------------------------------------------------
__global__ __launch_bounds__(256) void state_prefix(const float* __restrict__ sc,
                                                    float* __restrict__ states,
                                                    bf16* __restrict__ stb) {
  const int bh = blockIdx.x;
  const int e = blockIdx.y * 256 + threadIdx.x;
  if (e >= STATE_N) return;
  const float* scb = sc + (size_t)bh * (DH + 1) * DH;
  float run = scb[e];
  float* p = states + (size_t)bh * NC * STATE_N + e;
  if (e < 4096) {
    bf16* q = stb + (size_t)bh * NC * 4096 + e;
    for (int c = 0; c < NC; c++) {
      float tmp = p[(size_t)c * STATE_N];
      q[(size_t)c * 4096] = (bf16)run;
      run += tmp;
    }
  } else {
    for (int c = 0; c < NC; c++) {
      float tmp = p[(size_t)c * STATE_N];
      p[(size_t)c * STATE_N] = run;
      run += tmp;
    }
  }
}

// ---------------------------------------------------------------------------
// Pass 2: P = mask(Q K^T) (incl. diagonal), num = P@V + Q@S0,
// den = rowsum(P) + Q.z0, out = num/(den+eps).  grid (NC, BH) x 256 (4 waves).
// S0 now read as bf16 from stb (16B/lane vectorized); z0 fp32 from states.
// ---------------------------------------------------------------------------
__global__ __launch_bounds__(256) void attn_pass2(
    const bf16* __restrict__ qb, const bf16* __restrict__ kb,
    const bf16* __restrict__ vb, const float* __restrict__ states,
    const bf16* __restrict__ stb, bf16* __restrict__ ao) {
  constexpr int LD = 88;
  __shared__ bf16 Ql[CHUNK * LD];
  __shared__ bf16 Kl[CHUNK * LD];
  __shared__ bf16 VT[DH * LD];    // VT[e][j] = V[j][e]
  __shared__ bf16 S0T[DH * LD];   // S0T[e][d] = S0[d][e]
  __shared__ bf16 Pl[CHUNK * LD]; // masked P, row-major [t][j]
  __shared__ float denl[CHUNK];
  __shared__ float z0l[DH];
  const int tid = threadIdx.x;
  const int wave = tid >> 6, lane = tid & 63;
  const int quad = lane >> 4, l16 = lane & 15;
  const int c = blockIdx.x, bh = blockIdx.y;
  const int b = bh >> 4, h = bh & 15;
  const size_t gbase = ((size_t)(b * S_ + c * CHUNK)) * D_ + h * DH;

#pragma unroll
  for (int rep = 0; rep < 2; rep++) {
    int flat = tid + rep * 256;
    int r = flat >> 3, sg = (flat & 7) * 8;
    *(bf16x8*)&Ql[r * LD + sg] = *(const bf16x8*)(qb + gbase + (size_t)r * D_ + sg);
    *(bf16x8*)&Kl[r * LD + sg] = *(const bf16x8*)(kb + gbase + (size_t)r * D_ + sg);
    bf16x8 vv = *(const bf16x8*)(vb + gbase + (size_t)r * D_ + sg);
#pragma unroll
    for (int u = 0; u < 8; u++) VT[(sg + u) * LD + r] = vv[u];
  }
  // S0 staging from bf16 prefix states: thread handles 16 contiguous elems
  {
    const bf16* stb_c = stb + ((size_t)bh * NC + c) * 4096;
    const int f0 = tid * 16;
    const int col = f0 >> 6, row0 = f0 & 63;  // row0 in {0,16,32,48}
    bf16x8 a0 = *(const bf16x8*)&stb_c[f0];
    bf16x8 a1 = *(const bf16x8*)&stb_c[f0 + 8];
#pragma unroll
    for (int u = 0; u < 8; u++) {
      S0T[(row0 + u) * LD + col] = a0[u];
      S0T[(row0 + 8 + u) * LD + col] = a1[u];
    }
  }
  const float* st = states + ((size_t)bh * NC + c) * STATE_N;
  if (tid < DH) z0l[tid] = st[4096 + tid];
  __syncthreads();

  // phase 1: P = Q K^T
  v4f zero = {0.f, 0.f, 0.f, 0.f};
  v4f pacc[4];
#pragma unroll
  for (int j = 0; j < 4; j++) pacc[j] = zero;
#pragma unroll
  for (int ks = 0; ks < 2; ks++) {
    bf16x8 aq = *(const bf16x8*)&Ql[(wave * 16 + l16) * LD + ks * 32 + quad * 8];
#pragma unroll
    for (int j = 0; j < 4; j++) {
      bf16x8 bk = *(const bf16x8*)&Kl[(j * 16 + l16) * LD + ks * 32 + quad * 8];
      pacc[j] = MFMA16(aq, bk, pacc[j]);
    }
  }
  float rs[4] = {0.f, 0.f, 0.f, 0.f};
#pragma unroll
  for (int j = 0; j < 4; j++) {
#pragma unroll
    for (int r = 0; r < 4; r++) {
      int t = wave * 16 + quad * 4 + r;
      int col = j * 16 + l16;
      float p = (col <= t) ? pacc[j][r] : 0.f;
      Pl[t * LD + col] = (bf16)p;
      rs[r] += p;
    }
  }
#pragma unroll
  for (int m = 1; m < 16; m <<= 1)
#pragma unroll
    for (int r = 0; r < 4; r++) rs[r] += __shfl_xor(rs[r], m, 64);
  if (l16 == 0)
#pragma unroll
    for (int r = 0; r < 4; r++) denl[wave * 16 + quad * 4 + r] = rs[r];
  __syncthreads();
  if (tid < CHUNK) {
    float qz = 0.f;
    for (int d = 0; d < DH; d++) qz += (float)Ql[tid * LD + d] * z0l[d];
    denl[tid] += qz;
  }
  __syncthreads();

  // phase 2: num = P@V + Q@S0
  v4f nacc[4];
#pragma unroll
  for (int j = 0; j < 4; j++) nacc[j] = zero;
#pragma unroll
  for (int ks = 0; ks < 2; ks++) {
    bf16x8 ap = *(const bf16x8*)&Pl[(wave * 16 + l16) * LD + ks * 32 + quad * 8];
#pragma unroll
    for (int j = 0; j < 4; j++) {
      bf16x8 bv = *(const bf16x8*)&VT[(j * 16 + l16) * LD + ks * 32 + quad * 8];
      nacc[j] = MFMA16(ap, bv, nacc[j]);
    }
  }
#pragma unroll
  for (int ks = 0; ks < 2; ks++) {
    bf16x8 aq = *(const bf16x8*)&Ql[(wave * 16 + l16) * LD + ks * 32 + quad * 8];
#pragma unroll
    for (int j = 0; j < 4; j++) {
      bf16x8 bs = *(const bf16x8*)&S0T[(j * 16 + l16) * LD + ks * 32 + quad * 8];
      nacc[j] = MFMA16(aq, bs, nacc[j]);
    }
  }
#pragma unroll
  for (int j = 0; j < 4; j++) {
#pragma unroll
    for (int r = 0; r < 4; r++) {
      int t = wave * 16 + quad * 4 + r;
      int e = j * 16 + l16;
      float o = nacc[j][r] / (denl[t] + EPS);
      ao[gbase + (size_t)t * D_ + e] = (bf16)o;
    }
  }
}

// ---------------------------------------------------------------------------
extern "C" void kernel_launch(void* const* d_in, const int* in_sizes, int n_in,
                              void* d_out, int out_size, void* d_ws, size_t ws_size,
                              hipStream_t stream) {
  const float* x  = (const float*)d_in[0];
  const float* sc = (const float*)d_in[1];
  const float* Wq = (const float*)d_in[2];
  const float* Wk = (const float*)d_in[3];
  const float* Wv = (const float*)d_in[4];
  const float* Wo = (const float*)d_in[5];
  float* out = (float*)d_out;

  const size_t MSZ = (size_t)B_ * S_ * D_;  // 16,777,216 elems
  const size_t WSZ = (size_t)D_ * D_;       // 1,048,576 elems
  bf16* xb = (bf16*)d_ws;
  bf16* qb = xb + MSZ;
  bf16* kb = qb + MSZ;
  bf16* vb = kb + MSZ;
  bf16* ao = vb + MSZ;
  bf16* wt = ao + MSZ;  // 4 transposed bf16 weight matrices [q|k|v|o]
  float* states = (float*)(wt + 4 * WSZ);  // BH*NC*4160 fp32 (~68 MB)
  bf16* stb = xb;  // bf16 prefix states reuse xb (dead after QKV GEMM);
                   // BH*NC*4096 = 16,777,216 elems — exact fit.

  cvt_f32_bf16<<<MSZ / (256 * 8), 256, 0, stream>>>(x, xb);
  transpose_w4<<<dim3(32, 32, 4), 256, 0, stream>>>(Wq, Wk, Wv, Wo, wt);

  // fused QKV GEMM: BT rows 0..3071 span wt[q|k|v]
  gemm_nt<<<dim3(128, 24), 256, 0, stream>>>(xb, wt, qb, kb, vb, nullptr);

  chunk_kv<<<dim3(NC, BH), 256, 0, stream>>>(kb, vb, states);
  state_prefix<<<dim3(BH, 17), 256, 0, stream>>>(sc, states, stb);
  attn_pass2<<<dim3(NC, BH), 256, 0, stream>>>(qb, kb, vb, states, stb, ao);

  gemm_nt<<<dim3(128, 8), 256, 0, stream>>>(ao, wt + 3 * WSZ, nullptr, nullptr,
                                            nullptr, out);
}

// Round 4
// 415.462 us; speedup vs baseline: 2.4658x; 1.0096x over previous
//
#include <hip/hip_runtime.h>

#define B_ 4
#define S_ 4096
#define D_ 1024
#define H_ 16
#define DH 64
#define CHUNK 64
#define NC (S_ / CHUNK)   // 64 chunks
#define BH (B_ * H_)      // 64 (b,h) sequences
#define STATE_N 4160      // 64*64 S entries + 64 z entries
#define EPS 1e-6f

typedef __bf16 bf16;
typedef __bf16 bf16x8 __attribute__((ext_vector_type(8)));
typedef __bf16 bf16x4 __attribute__((ext_vector_type(4)));
typedef float v4f __attribute__((ext_vector_type(4)));

#define MFMA16(a, b, c) __builtin_amdgcn_mfma_f32_16x16x32_bf16(a, b, c, 0, 0, 0)

// async global->LDS, 16B per lane; LDS dest = wave-uniform base + lane*16
__device__ __forceinline__ void load_lds16(const bf16* g, bf16* l) {
  __builtin_amdgcn_global_load_lds(
      (const __attribute__((address_space(1))) unsigned int*)g,
      (__attribute__((address_space(3))) unsigned int*)l, 16, 0, 0);
}

// ---------------------------------------------------------------------------
// fp32 -> bf16 convert (x): 8 elems/thread, vectorized.
// ---------------------------------------------------------------------------
__global__ __launch_bounds__(256) void cvt_f32_bf16(const float* __restrict__ in,
                                                    bf16* __restrict__ out) {
  const size_t i = ((size_t)blockIdx.x * 256 + threadIdx.x) * 8;
  float4 a = *(const float4*)(in + i);
  float4 b = *(const float4*)(in + i + 4);
  bf16x8 o;
  o[0] = (bf16)a.x; o[1] = (bf16)a.y; o[2] = (bf16)a.z; o[3] = (bf16)a.w;
  o[4] = (bf16)b.x; o[5] = (bf16)b.y; o[6] = (bf16)b.z; o[7] = (bf16)b.w;
  *(bf16x8*)(out + i) = o;
}

// ---------------------------------------------------------------------------
// Fused weight transpose + fp32->bf16 for all 4 weights (z selects matrix).
// out[z][n*1024+k] = (bf16)W_z[k*1024+n]
// ---------------------------------------------------------------------------
__global__ __launch_bounds__(256) void transpose_w4(
    const float* __restrict__ w0, const float* __restrict__ w1,
    const float* __restrict__ w2, const float* __restrict__ w3,
    bf16* __restrict__ out) {
  __shared__ float tile[32][33];
  const int z = blockIdx.z;
  const float* in = (z == 0) ? w0 : (z == 1) ? w1 : (z == 2) ? w2 : w3;
  bf16* o = out + (size_t)z * D_ * D_;
  const int bx = blockIdx.x * 32, by = blockIdx.y * 32;
  const int tx = threadIdx.x & 31, ty = threadIdx.x >> 5;  // 32 x 8
#pragma unroll
  for (int i = 0; i < 32; i += 8)
    tile[ty + i][tx] = in[(size_t)(by + ty + i) * D_ + bx + tx];
  __syncthreads();
#pragma unroll
  for (int i = 0; i < 32; i += 8)
    o[(size_t)(bx + ty + i) * D_ + by + tx] = (bf16)tile[tx][ty + i];
}

// ---------------------------------------------------------------------------
// NT GEMM, double-buffered global_load_lds prefetch, SWIZZLED LDS staging.
// (Round-0 proven kernel. The 256x256 8-phase variant spilled ~1.1 GB of
// scratch to HBM on this compiler — do not retry without allocator evidence.)
// ---------------------------------------------------------------------------
__global__ __launch_bounds__(256) void gemm_nt(const bf16* __restrict__ A,
                                               const bf16* __restrict__ BT,
                                               bf16* __restrict__ o0,
                                               bf16* __restrict__ o1,
                                               bf16* __restrict__ o2,
                                               float* __restrict__ of) {
  constexpr int TM = 128, BK = 32;
  constexpr int CLD = 132;  // epilogue fp32 row stride
  __shared__ __align__(16) char smem[32768];  // 2 x (A 8KB + B 8KB); epilogue reuse
  float* Cl = (float*)smem;  // [32][132] fp32 (16896B)

  const int tid = threadIdx.x;
  const int wave = tid >> 6, lane = tid & 63;
  const int quad = lane >> 4, l16 = lane & 15;
  const int bm = blockIdx.x * TM;
  const int zz = blockIdx.y >> 3;
  const int colg = (blockIdx.y & 7) * 128;  // global col base of this tile
  const int wm = (wave & 1) * 64, wn = (wave >> 1) * 64;
  const int act = (of == nullptr) && (zz < 2);
  bf16* ob = (zz == 0) ? o0 : (zz == 1) ? o1 : o2;

  // staging: lane -> row wave*16 + lane/4 (+64 for 2nd call), swizzled group
  const int srow = wave * 16 + (lane >> 2);
  const int sgrp = ((lane & 3) - ((lane >> 2) >> 1)) & 3;  // swizzle
  const bf16* gA0 = A + (size_t)(bm + srow) * D_ + sgrp * 8;
  const bf16* gA1 = gA0 + (size_t)64 * D_;
  const bf16* gB0 = BT + ((size_t)blockIdx.y * 128 + srow) * D_ + sgrp * 8;
  const bf16* gB1 = gB0 + (size_t)64 * D_;

  // read-side swizzled (loop-invariant) fragment offsets
  int offA[4], offB[4];
#pragma unroll
  for (int i = 0; i < 4; i++) {
    const int pg = (quad + (l16 >> 1)) & 3;  // swizzled group
    offA[i] = (wm + i * 16 + l16) * BK + pg * 8;
    offB[i] = (wn + i * 16 + l16) * BK + pg * 8;
  }

  v4f zero = {0.f, 0.f, 0.f, 0.f};
  v4f acc[4][4];
#pragma unroll
  for (int i = 0; i < 4; i++)
#pragma unroll
    for (int j = 0; j < 4; j++) acc[i][j] = zero;

  auto stage = [&](int ks, int s) {
    bf16* As = (bf16*)(smem + s * 16384);
    bf16* Bs = As + 4096;
    const int ko = ks * BK;
    load_lds16(gA0 + ko, As + wave * 16 * BK);
    load_lds16(gA1 + ko, As + (64 + wave * 16) * BK);
    load_lds16(gB0 + ko, Bs + wave * 16 * BK);
    load_lds16(gB1 + ko, Bs + (64 + wave * 16) * BK);
  };
  auto compute = [&](int s) {
    const bf16* As = (const bf16*)(smem + s * 16384);
    const bf16* Bs = As + 4096;
    bf16x8 af[4], bfr[4];
#pragma unroll
    for (int i = 0; i < 4; i++) af[i] = *(const bf16x8*)&As[offA[i]];
#pragma unroll
    for (int j = 0; j < 4; j++) bfr[j] = *(const bf16x8*)&Bs[offB[j]];
#pragma unroll
    for (int i = 0; i < 4; i++)
#pragma unroll
      for (int j = 0; j < 4; j++) acc[i][j] = MFMA16(af[i], bfr[j], acc[i][j]);
  };

  constexpr int NK = D_ / BK;  // 32
  stage(0, 0);
  __syncthreads();  // slot 0 staged
  for (int k = 0; k < NK; k += 2) {
    if (k + 1 < NK) stage(k + 1, 1);  // in flight during compute(0)
    compute(0);
    __syncthreads();  // drains k+1 loads; slot-0 reads done
    if (k + 2 < NK) stage(k + 2, 0);
    compute(1);
    __syncthreads();
  }

  // ---- coalesced epilogue through LDS ----
  const int lr = (wave & 1) * 16 + quad * 4;
  const int rrow = tid >> 3;
  const int rseg = (tid & 7) * 16;
  const int grow = bm + (rrow >> 4) * 64 + (rrow & 15);
#pragma unroll
  for (int i = 0; i < 4; i++) {
    __syncthreads();
#pragma unroll
    for (int j = 0; j < 4; j++) {
      const int col = wn + j * 16 + l16;
#pragma unroll
      for (int r = 0; r < 4; r++) {
        float x = acc[i][j][r];
        if (act) x = x > 0.f ? x + 1.f : __expf(x);
        Cl[(lr + r) * CLD + col] = x;
      }
    }
    __syncthreads();
    const float* src = &Cl[rrow * CLD + rseg];
    if (of) {
      float* dst = of + (size_t)(grow + i * 16) * D_ + colg + rseg;
#pragma unroll
      for (int u = 0; u < 4; u++)
        *(float4*)(dst + u * 4) = *(const float4*)(src + u * 4);
    } else {
      bf16x8 q0, q1;
#pragma unroll
      for (int u = 0; u < 8; u++) { q0[u] = (bf16)src[u]; q1[u] = (bf16)src[8 + u]; }
      bf16* dst = ob + (size_t)(grow + i * 16) * D_ + colg + rseg;
      *(bf16x8*)dst = q0;
      *(bf16x8*)(dst + 8) = q1;
    }
  }
}

// ---------------------------------------------------------------------------
// Pass 1: per-chunk KV outer-product sums + k-sums, via MFMA.
// S[d][e] = sum_t K[t][d] V[t][e] = (K^T)(row d over t) . (V^T)(row e over t)
// Stage K,V transposed in LDS ([d][t] / [e][t], LD=72), 2 ks x 4 j MFMA/wave.
// Numerics identical to the VALU version (bf16 products, fp32 accumulate).
// grid (NC, BH) x 256.
// ---------------------------------------------------------------------------
__global__ __launch_bounds__(256) void chunk_kv(const bf16* __restrict__ kb,
                                                const bf16* __restrict__ vb,
                                                float* __restrict__ states) {
  constexpr int LD = 72;  // row stride (elems); row*144B keeps 16B alignment
  __shared__ bf16 KT[DH * LD];  // KT[d][t]
  __shared__ bf16 VT[DH * LD];  // VT[e][t]
  const int tid = threadIdx.x;
  const int wave = tid >> 6, lane = tid & 63;
  const int quad = lane >> 4, l16 = lane & 15;
  const int c = blockIdx.x, bh = blockIdx.y;
  const int b = bh >> 4, h = bh & 15;
  const size_t gbase = ((size_t)(b * S_ + c * CHUNK)) * D_ + h * DH;
#pragma unroll
  for (int rep = 0; rep < 2; rep++) {
    int flat = tid + rep * 256;
    int r = flat >> 3, sg = (flat & 7) * 8;  // r = t, sg = d0
    bf16x8 kk = *(const bf16x8*)(kb + gbase + (size_t)r * D_ + sg);
    bf16x8 vv = *(const bf16x8*)(vb + gbase + (size_t)r * D_ + sg);
#pragma unroll
    for (int u = 0; u < 8; u++) {
      KT[(sg + u) * LD + r] = kk[u];
      VT[(sg + u) * LD + r] = vv[u];
    }
  }
  __syncthreads();

  v4f zero = {0.f, 0.f, 0.f, 0.f};
  v4f acc[4];
#pragma unroll
  for (int j = 0; j < 4; j++) acc[j] = zero;
#pragma unroll
  for (int ks = 0; ks < 2; ks++) {
    bf16x8 ak = *(const bf16x8*)&KT[(wave * 16 + l16) * LD + ks * 32 + quad * 8];
#pragma unroll
    for (int j = 0; j < 4; j++) {
      bf16x8 bv = *(const bf16x8*)&VT[(j * 16 + l16) * LD + ks * 32 + quad * 8];
      acc[j] = MFMA16(ak, bv, acc[j]);
    }
  }
  float* out = states + ((size_t)bh * NC + c) * STATE_N;
#pragma unroll
  for (int j = 0; j < 4; j++)
#pragma unroll
    for (int r = 0; r < 4; r++)
      out[(wave * 16 + quad * 4 + r) * 64 + (j * 16 + l16)] = acc[j][r];

  // z[d] = sum_t K[t][d]: 4 lanes per d, 16 elems each, shfl reduce
  {
    const int d = tid >> 2, p = tid & 3;
    bf16x8 a0 = *(const bf16x8*)&KT[d * LD + p * 16];
    bf16x8 a1 = *(const bf16x8*)&KT[d * LD + p * 16 + 8];
    float zp = 0.f;
#pragma unroll
    for (int u = 0; u < 8; u++) zp += (float)a0[u] + (float)a1[u];
    zp += __shfl_xor(zp, 1, 64);
    zp += __shfl_xor(zp, 2, 64);
    if (p == 0) out[4096 + d] = zp;
  }
}

// ---------------------------------------------------------------------------
// Exclusive prefix over chunks + state_cache init (fp32 carry).
// 4-wide manual unroll: batch the 4 independent HBM loads ahead of the
// dependent prefix chain (breaks ~900-cycle serial load latency).
// S-part -> bf16 into stb; z-part fp32 in place.  grid (BH, 17) x 256.
// ---------------------------------------------------------------------------
__global__ __launch_bounds__(256) void state_prefix(const float* __restrict__ sc,
                                                    float* __restrict__ states,
                                                    bf16* __restrict__ stb) {
  const int bh = blockIdx.x;
  const int e = blockIdx.y * 256 + threadIdx.x;
  if (e >= STATE_N) return;
  const float* scb = sc + (size_t)bh * (DH + 1) * DH;
  float run = scb[e];
  float* p = states + (size_t)bh * NC * STATE_N + e;
  if (e < 4096) {
    bf16* q = stb + (size_t)bh * NC * 4096 + e;
#pragma unroll 1
    for (int c = 0; c < NC; c += 4) {
      float t0 = p[(size_t)(c + 0) * STATE_N];
      float t1 = p[(size_t)(c + 1) * STATE_N];
      float t2 = p[(size_t)(c + 2) * STATE_N];
      float t3 = p[(size_t)(c + 3) * STATE_N];
      q[(size_t)(c + 0) * 4096] = (bf16)run; run += t0;
      q[(size_t)(c + 1) * 4096] = (bf16)run; run += t1;
      q[(size_t)(c + 2) * 4096] = (bf16)run; run += t2;
      q[(size_t)(c + 3) * 4096] = (bf16)run; run += t3;
    }
  } else {
#pragma unroll 1
    for (int c = 0; c < NC; c += 4) {
      float t0 = p[(size_t)(c + 0) * STATE_N];
      float t1 = p[(size_t)(c + 1) * STATE_N];
      float t2 = p[(size_t)(c + 2) * STATE_N];
      float t3 = p[(size_t)(c + 3) * STATE_N];
      p[(size_t)(c + 0) * STATE_N] = run; run += t0;
      p[(size_t)(c + 1) * STATE_N] = run; run += t1;
      p[(size_t)(c + 2) * STATE_N] = run; run += t2;
      p[(size_t)(c + 3) * STATE_N] = run; run += t3;
    }
  }
}

// ---------------------------------------------------------------------------
// Pass 2: P = mask(Q K^T) (incl. diagonal), num = P@V + Q@S0,
// den = rowsum(P) + Q.z0, out = num/(den+eps).  grid (NC, BH) x 256 (4 waves).
// q.z0 now wave-parallel: 4 lanes/row x 16 elems + shfl_xor reduce.
// ---------------------------------------------------------------------------
__global__ __launch_bounds__(256) void attn_pass2(
    const bf16* __restrict__ qb, const bf16* __restrict__ kb,
    const bf16* __restrict__ vb, const float* __restrict__ states,
    const bf16* __restrict__ stb, bf16* __restrict__ ao) {
  constexpr int LD = 88;
  __shared__ bf16 Ql[CHUNK * LD];
  __shared__ bf16 Kl[CHUNK * LD];
  __shared__ bf16 VT[DH * LD];    // VT[e][j] = V[j][e]
  __shared__ bf16 S0T[DH * LD];   // S0T[e][d] = S0[d][e]
  __shared__ bf16 Pl[CHUNK * LD]; // masked P, row-major [t][j]
  __shared__ float denl[CHUNK];
  __shared__ float z0l[DH];
  const int tid = threadIdx.x;
  const int wave = tid >> 6, lane = tid & 63;
  const int quad = lane >> 4, l16 = lane & 15;
  const int c = blockIdx.x, bh = blockIdx.y;
  const int b = bh >> 4, h = bh & 15;
  const size_t gbase = ((size_t)(b * S_ + c * CHUNK)) * D_ + h * DH;

#pragma unroll
  for (int rep = 0; rep < 2; rep++) {
    int flat = tid + rep * 256;
    int r = flat >> 3, sg = (flat & 7) * 8;
    *(bf16x8*)&Ql[r * LD + sg] = *(const bf16x8*)(qb + gbase + (size_t)r * D_ + sg);
    *(bf16x8*)&Kl[r * LD + sg] = *(const bf16x8*)(kb + gbase + (size_t)r * D_ + sg);
    bf16x8 vv = *(const bf16x8*)(vb + gbase + (size_t)r * D_ + sg);
#pragma unroll
    for (int u = 0; u < 8; u++) VT[(sg + u) * LD + r] = vv[u];
  }
  // S0 staging from bf16 prefix states: thread handles 16 contiguous elems
  {
    const bf16* stb_c = stb + ((size_t)bh * NC + c) * 4096;
    const int f0 = tid * 16;
    const int col = f0 >> 6, row0 = f0 & 63;  // row0 in {0,16,32,48}
    bf16x8 a0 = *(const bf16x8*)&stb_c[f0];
    bf16x8 a1 = *(const bf16x8*)&stb_c[f0 + 8];
#pragma unroll
    for (int u = 0; u < 8; u++) {
      S0T[(row0 + u) * LD + col] = a0[u];
      S0T[(row0 + 8 + u) * LD + col] = a1[u];
    }
  }
  const float* st = states + ((size_t)bh * NC + c) * STATE_N;
  if (tid < DH) z0l[tid] = st[4096 + tid];
  __syncthreads();

  // phase 1: P = Q K^T
  v4f zero = {0.f, 0.f, 0.f, 0.f};
  v4f pacc[4];
#pragma unroll
  for (int j = 0; j < 4; j++) pacc[j] = zero;
#pragma unroll
  for (int ks = 0; ks < 2; ks++) {
    bf16x8 aq = *(const bf16x8*)&Ql[(wave * 16 + l16) * LD + ks * 32 + quad * 8];
#pragma unroll
    for (int j = 0; j < 4; j++) {
      bf16x8 bk = *(const bf16x8*)&Kl[(j * 16 + l16) * LD + ks * 32 + quad * 8];
      pacc[j] = MFMA16(aq, bk, pacc[j]);
    }
  }
  float rs[4] = {0.f, 0.f, 0.f, 0.f};
#pragma unroll
  for (int j = 0; j < 4; j++) {
#pragma unroll
    for (int r = 0; r < 4; r++) {
      int t = wave * 16 + quad * 4 + r;
      int col = j * 16 + l16;
      float p = (col <= t) ? pacc[j][r] : 0.f;
      Pl[t * LD + col] = (bf16)p;
      rs[r] += p;
    }
  }
#pragma unroll
  for (int m = 1; m < 16; m <<= 1)
#pragma unroll
    for (int r = 0; r < 4; r++) rs[r] += __shfl_xor(rs[r], m, 64);
  if (l16 == 0)
#pragma unroll
    for (int r = 0; r < 4; r++) denl[wave * 16 + quad * 4 + r] = rs[r];
  __syncthreads();
  // den += q . z0 (wave-parallel: t = tid>>2 covers 0..63, p = 16-elem slice)
  {
    const int t = tid >> 2, p = tid & 3;
    bf16x8 qa = *(const bf16x8*)&Ql[t * LD + p * 16];
    bf16x8 qb2 = *(const bf16x8*)&Ql[t * LD + p * 16 + 8];
    float qz = 0.f;
#pragma unroll
    for (int u = 0; u < 8; u++)
      qz += (float)qa[u] * z0l[p * 16 + u] + (float)qb2[u] * z0l[p * 16 + 8 + u];
    qz += __shfl_xor(qz, 1, 64);
    qz += __shfl_xor(qz, 2, 64);
    if (p == 0) denl[t] += qz;
  }
  __syncthreads();

  // phase 2: num = P@V + Q@S0
  v4f nacc[4];
#pragma unroll
  for (int j = 0; j < 4; j++) nacc[j] = zero;
#pragma unroll
  for (int ks = 0; ks < 2; ks++) {
    bf16x8 ap = *(const bf16x8*)&Pl[(wave * 16 + l16) * LD + ks * 32 + quad * 8];
#pragma unroll
    for (int j = 0; j < 4; j++) {
      bf16x8 bv = *(const bf16x8*)&VT[(j * 16 + l16) * LD + ks * 32 + quad * 8];
      nacc[j] = MFMA16(ap, bv, nacc[j]);
    }
  }
#pragma unroll
  for (int ks = 0; ks < 2; ks++) {
    bf16x8 aq = *(const bf16x8*)&Ql[(wave * 16 + l16) * LD + ks * 32 + quad * 8];
#pragma unroll
    for (int j = 0; j < 4; j++) {
      bf16x8 bs = *(const bf16x8*)&S0T[(j * 16 + l16) * LD + ks * 32 + quad * 8];
      nacc[j] = MFMA16(aq, bs, nacc[j]);
    }
  }
#pragma unroll
  for (int j = 0; j < 4; j++) {
#pragma unroll
    for (int r = 0; r < 4; r++) {
      int t = wave * 16 + quad * 4 + r;
      int e = j * 16 + l16;
      float o = nacc[j][r] / (denl[t] + EPS);
      ao[gbase + (size_t)t * D_ + e] = (bf16)o;
    }
  }
}

// ---------------------------------------------------------------------------
extern "C" void kernel_launch(void* const* d_in, const int* in_sizes, int n_in,
                              void* d_out, int out_size, void* d_ws, size_t ws_size,
                              hipStream_t stream) {
  const float* x  = (const float*)d_in[0];
  const float* sc = (const float*)d_in[1];
  const float* Wq = (const float*)d_in[2];
  const float* Wk = (const float*)d_in[3];
  const float* Wv = (const float*)d_in[4];
  const float* Wo = (const float*)d_in[5];
  float* out = (float*)d_out;

  const size_t MSZ = (size_t)B_ * S_ * D_;  // 16,777,216 elems
  const size_t WSZ = (size_t)D_ * D_;       // 1,048,576 elems
  bf16* xb = (bf16*)d_ws;
  bf16* qb = xb + MSZ;
  bf16* kb = qb + MSZ;
  bf16* vb = kb + MSZ;
  bf16* ao = vb + MSZ;
  bf16* wt = ao + MSZ;  // 4 transposed bf16 weight matrices [q|k|v|o]
  float* states = (float*)(wt + 4 * WSZ);  // BH*NC*4160 fp32 (~68 MB)
  bf16* stb = xb;  // bf16 prefix states reuse xb (dead after QKV GEMM);
                   // BH*NC*4096 = 16,777,216 elems — exact fit.

  cvt_f32_bf16<<<MSZ / (256 * 8), 256, 0, stream>>>(x, xb);
  transpose_w4<<<dim3(32, 32, 4), 256, 0, stream>>>(Wq, Wk, Wv, Wo, wt);

  // fused QKV GEMM: BT rows 0..3071 span wt[q|k|v]
  gemm_nt<<<dim3(128, 24), 256, 0, stream>>>(xb, wt, qb, kb, vb, nullptr);

  chunk_kv<<<dim3(NC, BH), 256, 0, stream>>>(kb, vb, states);
  state_prefix<<<dim3(BH, 17), 256, 0, stream>>>(sc, states, stb);
  attn_pass2<<<dim3(NC, BH), 256, 0, stream>>>(qb, kb, vb, states, stb, ao);

  gemm_nt<<<dim3(128, 8), 256, 0, stream>>>(ao, wt + 3 * WSZ, nullptr, nullptr,
                                            nullptr, out);
}

// Round 5
// 392.337 us; speedup vs baseline: 2.6111x; 1.0589x over previous
//
#include <hip/hip_runtime.h>

#define B_ 4
#define S_ 4096
#define D_ 1024
#define H_ 16
#define DH 64
#define CHUNK 64
#define NC (S_ / CHUNK)   // 64 chunks
#define BH (B_ * H_)      // 64 (b,h) sequences
#define EPS 1e-6f

typedef __bf16 bf16;
typedef __bf16 bf16x8 __attribute__((ext_vector_type(8)));
typedef __bf16 bf16x4 __attribute__((ext_vector_type(4)));
typedef float v4f __attribute__((ext_vector_type(4)));

#define MFMA16(a, b, c) __builtin_amdgcn_mfma_f32_16x16x32_bf16(a, b, c, 0, 0, 0)

// async global->LDS, 16B per lane; LDS dest = wave-uniform base + lane*16
__device__ __forceinline__ void load_lds16(const bf16* g, bf16* l) {
  __builtin_amdgcn_global_load_lds(
      (const __attribute__((address_space(1))) unsigned int*)g,
      (__attribute__((address_space(3))) unsigned int*)l, 16, 0, 0);
}

// ---------------------------------------------------------------------------
// fp32 -> bf16 convert (x): 8 elems/thread, vectorized.
// ---------------------------------------------------------------------------
__global__ __launch_bounds__(256) void cvt_f32_bf16(const float* __restrict__ in,
                                                    bf16* __restrict__ out) {
  const size_t i = ((size_t)blockIdx.x * 256 + threadIdx.x) * 8;
  float4 a = *(const float4*)(in + i);
  float4 b = *(const float4*)(in + i + 4);
  bf16x8 o;
  o[0] = (bf16)a.x; o[1] = (bf16)a.y; o[2] = (bf16)a.z; o[3] = (bf16)a.w;
  o[4] = (bf16)b.x; o[5] = (bf16)b.y; o[6] = (bf16)b.z; o[7] = (bf16)b.w;
  *(bf16x8*)(out + i) = o;
}

// ---------------------------------------------------------------------------
// Fused weight transpose + fp32->bf16 for all 4 weights (z selects matrix).
// out[z][n*1024+k] = (bf16)W_z[k*1024+n]
// ---------------------------------------------------------------------------
__global__ __launch_bounds__(256) void transpose_w4(
    const float* __restrict__ w0, const float* __restrict__ w1,
    const float* __restrict__ w2, const float* __restrict__ w3,
    bf16* __restrict__ out) {
  __shared__ float tile[32][33];
  const int z = blockIdx.z;
  const float* in = (z == 0) ? w0 : (z == 1) ? w1 : (z == 2) ? w2 : w3;
  bf16* o = out + (size_t)z * D_ * D_;
  const int bx = blockIdx.x * 32, by = blockIdx.y * 32;
  const int tx = threadIdx.x & 31, ty = threadIdx.x >> 5;  // 32 x 8
#pragma unroll
  for (int i = 0; i < 32; i += 8)
    tile[ty + i][tx] = in[(size_t)(by + ty + i) * D_ + bx + tx];
  __syncthreads();
#pragma unroll
  for (int i = 0; i < 32; i += 8)
    o[(size_t)(bx + ty + i) * D_ + by + tx] = (bf16)tile[tx][ty + i];
}

// ---------------------------------------------------------------------------
// NT GEMM, double-buffered global_load_lds prefetch, SWIZZLED LDS staging.
// (Round-0 proven kernel. The 256x256 8-phase variant spilled ~1.1 GB of
// scratch to HBM on this compiler — do not retry without allocator evidence.
// 32x32x16 MFMA rejected: lane=row over 32 rows + 16B gload_lds slots gives
// an inherent 4-way LDS read conflict — analysis round 4.)
// ---------------------------------------------------------------------------
__global__ __launch_bounds__(256) void gemm_nt(const bf16* __restrict__ A,
                                               const bf16* __restrict__ BT,
                                               bf16* __restrict__ o0,
                                               bf16* __restrict__ o1,
                                               bf16* __restrict__ o2,
                                               float* __restrict__ of) {
  constexpr int TM = 128, BK = 32;
  constexpr int CLD = 132;  // epilogue fp32 row stride
  __shared__ __align__(16) char smem[32768];  // 2 x (A 8KB + B 8KB); epilogue reuse
  float* Cl = (float*)smem;  // [32][132] fp32 (16896B)

  const int tid = threadIdx.x;
  const int wave = tid >> 6, lane = tid & 63;
  const int quad = lane >> 4, l16 = lane & 15;
  const int bm = blockIdx.x * TM;
  const int zz = blockIdx.y >> 3;
  const int colg = (blockIdx.y & 7) * 128;  // global col base of this tile
  const int wm = (wave & 1) * 64, wn = (wave >> 1) * 64;
  const int act = (of == nullptr) && (zz < 2);
  bf16* ob = (zz == 0) ? o0 : (zz == 1) ? o1 : o2;

  // staging: lane -> row wave*16 + lane/4 (+64 for 2nd call), swizzled group
  const int srow = wave * 16 + (lane >> 2);
  const int sgrp = ((lane & 3) - ((lane >> 2) >> 1)) & 3;  // swizzle
  const bf16* gA0 = A + (size_t)(bm + srow) * D_ + sgrp * 8;
  const bf16* gA1 = gA0 + (size_t)64 * D_;
  const bf16* gB0 = BT + ((size_t)blockIdx.y * 128 + srow) * D_ + sgrp * 8;
  const bf16* gB1 = gB0 + (size_t)64 * D_;

  // read-side swizzled (loop-invariant) fragment offsets
  int offA[4], offB[4];
#pragma unroll
  for (int i = 0; i < 4; i++) {
    const int pg = (quad + (l16 >> 1)) & 3;  // swizzled group
    offA[i] = (wm + i * 16 + l16) * BK + pg * 8;
    offB[i] = (wn + i * 16 + l16) * BK + pg * 8;
  }

  v4f zero = {0.f, 0.f, 0.f, 0.f};
  v4f acc[4][4];
#pragma unroll
  for (int i = 0; i < 4; i++)
#pragma unroll
    for (int j = 0; j < 4; j++) acc[i][j] = zero;

  auto stage = [&](int ks, int s) {
    bf16* As = (bf16*)(smem + s * 16384);
    bf16* Bs = As + 4096;
    const int ko = ks * BK;
    load_lds16(gA0 + ko, As + wave * 16 * BK);
    load_lds16(gA1 + ko, As + (64 + wave * 16) * BK);
    load_lds16(gB0 + ko, Bs + wave * 16 * BK);
    load_lds16(gB1 + ko, Bs + (64 + wave * 16) * BK);
  };
  auto compute = [&](int s) {
    const bf16* As = (const bf16*)(smem + s * 16384);
    const bf16* Bs = As + 4096;
    bf16x8 af[4], bfr[4];
#pragma unroll
    for (int i = 0; i < 4; i++) af[i] = *(const bf16x8*)&As[offA[i]];
#pragma unroll
    for (int j = 0; j < 4; j++) bfr[j] = *(const bf16x8*)&Bs[offB[j]];
#pragma unroll
    for (int i = 0; i < 4; i++)
#pragma unroll
      for (int j = 0; j < 4; j++) acc[i][j] = MFMA16(af[i], bfr[j], acc[i][j]);
  };

  constexpr int NK = D_ / BK;  // 32
  stage(0, 0);
  __syncthreads();  // slot 0 staged
  for (int k = 0; k < NK; k += 2) {
    if (k + 1 < NK) stage(k + 1, 1);  // in flight during compute(0)
    compute(0);
    __syncthreads();  // drains k+1 loads; slot-0 reads done
    if (k + 2 < NK) stage(k + 2, 0);
    compute(1);
    __syncthreads();
  }

  // ---- coalesced epilogue through LDS ----
  const int lr = (wave & 1) * 16 + quad * 4;
  const int rrow = tid >> 3;
  const int rseg = (tid & 7) * 16;
  const int grow = bm + (rrow >> 4) * 64 + (rrow & 15);
#pragma unroll
  for (int i = 0; i < 4; i++) {
    __syncthreads();
#pragma unroll
    for (int j = 0; j < 4; j++) {
      const int col = wn + j * 16 + l16;
#pragma unroll
      for (int r = 0; r < 4; r++) {
        float x = acc[i][j][r];
        if (act) x = x > 0.f ? x + 1.f : __expf(x);
        Cl[(lr + r) * CLD + col] = x;
      }
    }
    __syncthreads();
    const float* src = &Cl[rrow * CLD + rseg];
    if (of) {
      float* dst = of + (size_t)(grow + i * 16) * D_ + colg + rseg;
#pragma unroll
      for (int u = 0; u < 4; u++)
        *(float4*)(dst + u * 4) = *(const float4*)(src + u * 4);
    } else {
      bf16x8 q0, q1;
#pragma unroll
      for (int u = 0; u < 8; u++) { q0[u] = (bf16)src[u]; q1[u] = (bf16)src[8 + u]; }
      bf16* dst = ob + (size_t)(grow + i * 16) * D_ + colg + rseg;
      *(bf16x8*)dst = q0;
      *(bf16x8*)(dst + 8) = q1;
    }
  }
}

// ---------------------------------------------------------------------------
// Pass 1: per-chunk KV outer-product sums (bf16 out) + k-sums (fp32), MFMA.
// csum[bh][c][d*64+e] = (bf16) sum_t k[t][d]*v[t][e];  zbuf[bh][c][d] = sum k
// bf16 chunk sums: the prefix output was already bf16-rounded, so this adds
// at most sqrt(2)x the existing rounding noise.  grid (NC, BH) x 256.
// ---------------------------------------------------------------------------
__global__ __launch_bounds__(256) void chunk_kv(const bf16* __restrict__ kb,
                                                const bf16* __restrict__ vb,
                                                bf16* __restrict__ csum,
                                                float* __restrict__ zbuf) {
  constexpr int LD = 72;  // row stride (elems); row*144B keeps 16B alignment
  __shared__ __align__(16) bf16 KT[DH * LD];  // KT[d][t]
  __shared__ __align__(16) bf16 VT[DH * LD];  // VT[e][t]
  const int tid = threadIdx.x;
  const int wave = tid >> 6, lane = tid & 63;
  const int quad = lane >> 4, l16 = lane & 15;
  const int c = blockIdx.x, bh = blockIdx.y;
  const int b = bh >> 4, h = bh & 15;
  const size_t gbase = ((size_t)(b * S_ + c * CHUNK)) * D_ + h * DH;
#pragma unroll
  for (int rep = 0; rep < 2; rep++) {
    int flat = tid + rep * 256;
    int r = flat >> 3, sg = (flat & 7) * 8;  // r = t, sg = d0
    bf16x8 kk = *(const bf16x8*)(kb + gbase + (size_t)r * D_ + sg);
    bf16x8 vv = *(const bf16x8*)(vb + gbase + (size_t)r * D_ + sg);
#pragma unroll
    for (int u = 0; u < 8; u++) {
      KT[(sg + u) * LD + r] = kk[u];
      VT[(sg + u) * LD + r] = vv[u];
    }
  }
  __syncthreads();

  v4f zero = {0.f, 0.f, 0.f, 0.f};
  v4f acc[4];
#pragma unroll
  for (int j = 0; j < 4; j++) acc[j] = zero;
#pragma unroll
  for (int ks = 0; ks < 2; ks++) {
    bf16x8 ak = *(const bf16x8*)&KT[(wave * 16 + l16) * LD + ks * 32 + quad * 8];
#pragma unroll
    for (int j = 0; j < 4; j++) {
      bf16x8 bv = *(const bf16x8*)&VT[(j * 16 + l16) * LD + ks * 32 + quad * 8];
      acc[j] = MFMA16(ak, bv, acc[j]);
    }
  }
  bf16* out = csum + ((size_t)bh * NC + c) * 4096;
#pragma unroll
  for (int j = 0; j < 4; j++)
#pragma unroll
    for (int r = 0; r < 4; r++)
      out[(wave * 16 + quad * 4 + r) * 64 + (j * 16 + l16)] = (bf16)acc[j][r];

  // z[d] = sum_t K[t][d]: 4 lanes per d, 16 elems each, shfl reduce (fp32)
  {
    const int d = tid >> 2, p = tid & 3;
    bf16x8 a0 = *(const bf16x8*)&KT[d * LD + p * 16];
    bf16x8 a1 = *(const bf16x8*)&KT[d * LD + p * 16 + 8];
    float zp = 0.f;
#pragma unroll
    for (int u = 0; u < 8; u++) zp += (float)a0[u] + (float)a1[u];
    zp += __shfl_xor(zp, 1, 64);
    zp += __shfl_xor(zp, 2, 64);
    if (p == 0) zbuf[((size_t)bh * NC + c) * 64 + d] = zp;
  }
}

// ---------------------------------------------------------------------------
// Exclusive prefix over chunks + state_cache init (fp32 carry).
// S-part: read bf16 csum, write bf16 exclusive-prefix into stb.
// z-part: fp32 in place in zbuf.  grid (BH, 17) x 256.
// 4-wide load batching breaks the ~900-cycle serial HBM latency chain.
// ---------------------------------------------------------------------------
__global__ __launch_bounds__(256) void state_prefix(const float* __restrict__ sc,
                                                    const bf16* __restrict__ csum,
                                                    float* __restrict__ zbuf,
                                                    bf16* __restrict__ stb) {
  const int bh = blockIdx.x;
  const int e = blockIdx.y * 256 + threadIdx.x;
  const float* scb = sc + (size_t)bh * (DH + 1) * DH;
  if (e < 4096) {
    float run = scb[e];
    const bf16* p = csum + (size_t)bh * NC * 4096 + e;
    bf16* q = stb + (size_t)bh * NC * 4096 + e;
#pragma unroll 1
    for (int c = 0; c < NC; c += 4) {
      float t0 = (float)p[(size_t)(c + 0) * 4096];
      float t1 = (float)p[(size_t)(c + 1) * 4096];
      float t2 = (float)p[(size_t)(c + 2) * 4096];
      float t3 = (float)p[(size_t)(c + 3) * 4096];
      q[(size_t)(c + 0) * 4096] = (bf16)run; run += t0;
      q[(size_t)(c + 1) * 4096] = (bf16)run; run += t1;
      q[(size_t)(c + 2) * 4096] = (bf16)run; run += t2;
      q[(size_t)(c + 3) * 4096] = (bf16)run; run += t3;
    }
  } else if (e < 4160) {
    const int d = e - 4096;
    float run = scb[4096 + d];
    float* p = zbuf + (size_t)bh * NC * 64 + d;
#pragma unroll 1
    for (int c = 0; c < NC; c += 4) {
      float t0 = p[(size_t)(c + 0) * 64];
      float t1 = p[(size_t)(c + 1) * 64];
      float t2 = p[(size_t)(c + 2) * 64];
      float t3 = p[(size_t)(c + 3) * 64];
      p[(size_t)(c + 0) * 64] = run; run += t0;
      p[(size_t)(c + 1) * 64] = run; run += t1;
      p[(size_t)(c + 2) * 64] = run; run += t2;
      p[(size_t)(c + 3) * 64] = run; run += t3;
    }
  }
}

// ---------------------------------------------------------------------------
// Pass 2: P = mask(Q K^T) (incl. diagonal), num = P@V + Q@S0,
// den = rowsum(P) + Q.z0, out = num/(den+eps).  grid (NC, BH) x 256 (4 waves).
// LD=72 (was 88): LDS 56.8 -> 46.6 KB -> 3 blocks/CU (+50% occupancy).
// 144B row stride: bank-start row*4 mod 32 -> 2-way alias only (free).
// ---------------------------------------------------------------------------
__global__ __launch_bounds__(256) void attn_pass2(
    const bf16* __restrict__ qb, const bf16* __restrict__ kb,
    const bf16* __restrict__ vb, const float* __restrict__ zbuf,
    const bf16* __restrict__ stb, bf16* __restrict__ ao) {
  constexpr int LD = 72;
  __shared__ __align__(16) bf16 Ql[CHUNK * LD];
  __shared__ __align__(16) bf16 Kl[CHUNK * LD];
  __shared__ __align__(16) bf16 VT[DH * LD];    // VT[e][j] = V[j][e]
  __shared__ __align__(16) bf16 S0T[DH * LD];   // S0T[e][d] = S0[d][e]
  __shared__ __align__(16) bf16 Pl[CHUNK * LD]; // masked P, row-major [t][j]
  __shared__ float denl[CHUNK];
  __shared__ float z0l[DH];
  const int tid = threadIdx.x;
  const int wave = tid >> 6, lane = tid & 63;
  const int quad = lane >> 4, l16 = lane & 15;
  const int c = blockIdx.x, bh = blockIdx.y;
  const int b = bh >> 4, h = bh & 15;
  const size_t gbase = ((size_t)(b * S_ + c * CHUNK)) * D_ + h * DH;

#pragma unroll
  for (int rep = 0; rep < 2; rep++) {
    int flat = tid + rep * 256;
    int r = flat >> 3, sg = (flat & 7) * 8;
    *(bf16x8*)&Ql[r * LD + sg] = *(const bf16x8*)(qb + gbase + (size_t)r * D_ + sg);
    *(bf16x8*)&Kl[r * LD + sg] = *(const bf16x8*)(kb + gbase + (size_t)r * D_ + sg);
    bf16x8 vv = *(const bf16x8*)(vb + gbase + (size_t)r * D_ + sg);
#pragma unroll
    for (int u = 0; u < 8; u++) VT[(sg + u) * LD + r] = vv[u];
  }
  // S0 staging from bf16 prefix states: thread handles 16 contiguous elems
  {
    const bf16* stb_c = stb + ((size_t)bh * NC + c) * 4096;
    const int f0 = tid * 16;
    const int col = f0 >> 6, row0 = f0 & 63;  // row0 in {0,16,32,48}
    bf16x8 a0 = *(const bf16x8*)&stb_c[f0];
    bf16x8 a1 = *(const bf16x8*)&stb_c[f0 + 8];
#pragma unroll
    for (int u = 0; u < 8; u++) {
      S0T[(row0 + u) * LD + col] = a0[u];
      S0T[(row0 + 8 + u) * LD + col] = a1[u];
    }
  }
  if (tid < DH) z0l[tid] = zbuf[((size_t)bh * NC + c) * 64 + tid];
  __syncthreads();

  // phase 1: P = Q K^T
  v4f zero = {0.f, 0.f, 0.f, 0.f};
  v4f pacc[4];
#pragma unroll
  for (int j = 0; j < 4; j++) pacc[j] = zero;
#pragma unroll
  for (int ks = 0; ks < 2; ks++) {
    bf16x8 aq = *(const bf16x8*)&Ql[(wave * 16 + l16) * LD + ks * 32 + quad * 8];
#pragma unroll
    for (int j = 0; j < 4; j++) {
      bf16x8 bk = *(const bf16x8*)&Kl[(j * 16 + l16) * LD + ks * 32 + quad * 8];
      pacc[j] = MFMA16(aq, bk, pacc[j]);
    }
  }
  float rs[4] = {0.f, 0.f, 0.f, 0.f};
#pragma unroll
  for (int j = 0; j < 4; j++) {
#pragma unroll
    for (int r = 0; r < 4; r++) {
      int t = wave * 16 + quad * 4 + r;
      int col = j * 16 + l16;
      float p = (col <= t) ? pacc[j][r] : 0.f;
      Pl[t * LD + col] = (bf16)p;
      rs[r] += p;
    }
  }
#pragma unroll
  for (int m = 1; m < 16; m <<= 1)
#pragma unroll
    for (int r = 0; r < 4; r++) rs[r] += __shfl_xor(rs[r], m, 64);
  if (l16 == 0)
#pragma unroll
    for (int r = 0; r < 4; r++) denl[wave * 16 + quad * 4 + r] = rs[r];
  __syncthreads();
  // den += q . z0 (wave-parallel: t = tid>>2 covers 0..63, p = 16-elem slice)
  {
    const int t = tid >> 2, p = tid & 3;
    bf16x8 qa = *(const bf16x8*)&Ql[t * LD + p * 16];
    bf16x8 qb2 = *(const bf16x8*)&Ql[t * LD + p * 16 + 8];
    float qz = 0.f;
#pragma unroll
    for (int u = 0; u < 8; u++)
      qz += (float)qa[u] * z0l[p * 16 + u] + (float)qb2[u] * z0l[p * 16 + 8 + u];
    qz += __shfl_xor(qz, 1, 64);
    qz += __shfl_xor(qz, 2, 64);
    if (p == 0) denl[t] += qz;
  }
  __syncthreads();

  // phase 2: num = P@V + Q@S0
  v4f nacc[4];
#pragma unroll
  for (int j = 0; j < 4; j++) nacc[j] = zero;
#pragma unroll
  for (int ks = 0; ks < 2; ks++) {
    bf16x8 ap = *(const bf16x8*)&Pl[(wave * 16 + l16) * LD + ks * 32 + quad * 8];
#pragma unroll
    for (int j = 0; j < 4; j++) {
      bf16x8 bv = *(const bf16x8*)&VT[(j * 16 + l16) * LD + ks * 32 + quad * 8];
      nacc[j] = MFMA16(ap, bv, nacc[j]);
    }
  }
#pragma unroll
  for (int ks = 0; ks < 2; ks++) {
    bf16x8 aq = *(const bf16x8*)&Ql[(wave * 16 + l16) * LD + ks * 32 + quad * 8];
#pragma unroll
    for (int j = 0; j < 4; j++) {
      bf16x8 bs = *(const bf16x8*)&S0T[(j * 16 + l16) * LD + ks * 32 + quad * 8];
      nacc[j] = MFMA16(aq, bs, nacc[j]);
    }
  }
#pragma unroll
  for (int j = 0; j < 4; j++) {
#pragma unroll
    for (int r = 0; r < 4; r++) {
      int t = wave * 16 + quad * 4 + r;
      int e = j * 16 + l16;
      float o = nacc[j][r] / (denl[t] + EPS);
      ao[gbase + (size_t)t * D_ + e] = (bf16)o;
    }
  }
}

// ---------------------------------------------------------------------------
extern "C" void kernel_launch(void* const* d_in, const int* in_sizes, int n_in,
                              void* d_out, int out_size, void* d_ws, size_t ws_size,
                              hipStream_t stream) {
  const float* x  = (const float*)d_in[0];
  const float* sc = (const float*)d_in[1];
  const float* Wq = (const float*)d_in[2];
  const float* Wk = (const float*)d_in[3];
  const float* Wv = (const float*)d_in[4];
  const float* Wo = (const float*)d_in[5];
  float* out = (float*)d_out;

  const size_t MSZ = (size_t)B_ * S_ * D_;  // 16,777,216 elems
  const size_t WSZ = (size_t)D_ * D_;       // 1,048,576 elems
  bf16* xb = (bf16*)d_ws;
  bf16* qb = xb + MSZ;
  bf16* kb = qb + MSZ;
  bf16* vb = kb + MSZ;
  bf16* ao = vb + MSZ;
  bf16* wt = ao + MSZ;  // 4 transposed bf16 weight matrices [q|k|v|o]
  bf16* csum = wt + 4 * WSZ;            // bf16 chunk sums: BH*NC*4096 (32 MB)
  float* zbuf = (float*)(csum + (size_t)BH * NC * 4096);  // fp32 z: 1 MB
  bf16* stb = xb;  // bf16 prefix states reuse xb (dead after QKV GEMM);
                   // BH*NC*4096 = 16,777,216 elems — exact fit.

  cvt_f32_bf16<<<MSZ / (256 * 8), 256, 0, stream>>>(x, xb);
  transpose_w4<<<dim3(32, 32, 4), 256, 0, stream>>>(Wq, Wk, Wv, Wo, wt);

  // fused QKV GEMM: BT rows 0..3071 span wt[q|k|v]
  gemm_nt<<<dim3(128, 24), 256, 0, stream>>>(xb, wt, qb, kb, vb, nullptr);

  chunk_kv<<<dim3(NC, BH), 256, 0, stream>>>(kb, vb, csum, zbuf);
  state_prefix<<<dim3(BH, 17), 256, 0, stream>>>(sc, csum, zbuf, stb);
  attn_pass2<<<dim3(NC, BH), 256, 0, stream>>>(qb, kb, vb, zbuf, stb, ao);

  gemm_nt<<<dim3(128, 8), 256, 0, stream>>>(ao, wt + 3 * WSZ, nullptr, nullptr,
                                            nullptr, out);
}

// Round 6
// 387.649 us; speedup vs baseline: 2.6427x; 1.0121x over previous
//
#include <hip/hip_runtime.h>

#define B_ 4
#define S_ 4096
#define D_ 1024
#define H_ 16
#define DH 64
#define CHUNK 64
#define NC (S_ / CHUNK)   // 64 chunks
#define BH (B_ * H_)      // 64 (b,h) sequences
#define EPS 1e-6f

typedef __bf16 bf16;
typedef __bf16 bf16x8 __attribute__((ext_vector_type(8)));
typedef __bf16 bf16x4 __attribute__((ext_vector_type(4)));
typedef float v4f __attribute__((ext_vector_type(4)));

#define MFMA16(a, b, c) __builtin_amdgcn_mfma_f32_16x16x32_bf16(a, b, c, 0, 0, 0)

// async global->LDS, 16B per lane; LDS dest = wave-uniform base + lane*16
__device__ __forceinline__ void load_lds16(const bf16* g, bf16* l) {
  __builtin_amdgcn_global_load_lds(
      (const __attribute__((address_space(1))) unsigned int*)g,
      (__attribute__((address_space(3))) unsigned int*)l, 16, 0, 0);
}

// ---------------------------------------------------------------------------
// XOR-swizzled element offset for [64][72] bf16 LDS tiles.
// Logical (row,col) -> row*72 + ((col>>3 ^ row>>3)&7)*8 + (col&7).
// Bijection per row; 8-aligned col groups stay contiguous (b128-safe).
// Turns the transpose-scatter's 8-way bank conflict (36*8k = 0 mod 32)
// into <=2-way; b128 reads remain at the 8-pass minimum.
// ---------------------------------------------------------------------------
__device__ __forceinline__ int swz72(int row, int col) {
  return row * 72 + ((((col >> 3) ^ (row >> 3)) & 7) << 3) + (col & 7);
}

// ---------------------------------------------------------------------------
// fp32 -> bf16 convert (x): 8 elems/thread, vectorized.
// ---------------------------------------------------------------------------
__global__ __launch_bounds__(256) void cvt_f32_bf16(const float* __restrict__ in,
                                                    bf16* __restrict__ out) {
  const size_t i = ((size_t)blockIdx.x * 256 + threadIdx.x) * 8;
  float4 a = *(const float4*)(in + i);
  float4 b = *(const float4*)(in + i + 4);
  bf16x8 o;
  o[0] = (bf16)a.x; o[1] = (bf16)a.y; o[2] = (bf16)a.z; o[3] = (bf16)a.w;
  o[4] = (bf16)b.x; o[5] = (bf16)b.y; o[6] = (bf16)b.z; o[7] = (bf16)b.w;
  *(bf16x8*)(out + i) = o;
}

// ---------------------------------------------------------------------------
// Fused weight transpose + fp32->bf16 for all 4 weights (z selects matrix).
// ---------------------------------------------------------------------------
__global__ __launch_bounds__(256) void transpose_w4(
    const float* __restrict__ w0, const float* __restrict__ w1,
    const float* __restrict__ w2, const float* __restrict__ w3,
    bf16* __restrict__ out) {
  __shared__ float tile[32][33];
  const int z = blockIdx.z;
  const float* in = (z == 0) ? w0 : (z == 1) ? w1 : (z == 2) ? w2 : w3;
  bf16* o = out + (size_t)z * D_ * D_;
  const int bx = blockIdx.x * 32, by = blockIdx.y * 32;
  const int tx = threadIdx.x & 31, ty = threadIdx.x >> 5;  // 32 x 8
#pragma unroll
  for (int i = 0; i < 32; i += 8)
    tile[ty + i][tx] = in[(size_t)(by + ty + i) * D_ + bx + tx];
  __syncthreads();
#pragma unroll
  for (int i = 0; i < 32; i += 8)
    o[(size_t)(bx + ty + i) * D_ + by + tx] = (bf16)tile[tx][ty + i];
}

// ---------------------------------------------------------------------------
// NT GEMM, double-buffered global_load_lds prefetch, SWIZZLED LDS staging.
// (Round-0 proven kernel. The 256x256 8-phase variant spilled ~1.1 GB of
// scratch to HBM on this compiler — do not retry without allocator evidence.
// 32x32x16 MFMA rejected: analysis round 4.)
// ---------------------------------------------------------------------------
__global__ __launch_bounds__(256) void gemm_nt(const bf16* __restrict__ A,
                                               const bf16* __restrict__ BT,
                                               bf16* __restrict__ o0,
                                               bf16* __restrict__ o1,
                                               bf16* __restrict__ o2,
                                               float* __restrict__ of) {
  constexpr int TM = 128, BK = 32;
  constexpr int CLD = 132;  // epilogue fp32 row stride
  __shared__ __align__(16) char smem[32768];  // 2 x (A 8KB + B 8KB); epilogue reuse
  float* Cl = (float*)smem;  // [32][132] fp32 (16896B)

  const int tid = threadIdx.x;
  const int wave = tid >> 6, lane = tid & 63;
  const int quad = lane >> 4, l16 = lane & 15;
  const int bm = blockIdx.x * TM;
  const int zz = blockIdx.y >> 3;
  const int colg = (blockIdx.y & 7) * 128;  // global col base of this tile
  const int wm = (wave & 1) * 64, wn = (wave >> 1) * 64;
  const int act = (of == nullptr) && (zz < 2);
  bf16* ob = (zz == 0) ? o0 : (zz == 1) ? o1 : o2;

  // staging: lane -> row wave*16 + lane/4 (+64 for 2nd call), swizzled group
  const int srow = wave * 16 + (lane >> 2);
  const int sgrp = ((lane & 3) - ((lane >> 2) >> 1)) & 3;  // swizzle
  const bf16* gA0 = A + (size_t)(bm + srow) * D_ + sgrp * 8;
  const bf16* gA1 = gA0 + (size_t)64 * D_;
  const bf16* gB0 = BT + ((size_t)blockIdx.y * 128 + srow) * D_ + sgrp * 8;
  const bf16* gB1 = gB0 + (size_t)64 * D_;

  // read-side swizzled (loop-invariant) fragment offsets
  int offA[4], offB[4];
#pragma unroll
  for (int i = 0; i < 4; i++) {
    const int pg = (quad + (l16 >> 1)) & 3;  // swizzled group
    offA[i] = (wm + i * 16 + l16) * BK + pg * 8;
    offB[i] = (wn + i * 16 + l16) * BK + pg * 8;
  }

  v4f zero = {0.f, 0.f, 0.f, 0.f};
  v4f acc[4][4];
#pragma unroll
  for (int i = 0; i < 4; i++)
#pragma unroll
    for (int j = 0; j < 4; j++) acc[i][j] = zero;

  auto stage = [&](int ks, int s) {
    bf16* As = (bf16*)(smem + s * 16384);
    bf16* Bs = As + 4096;
    const int ko = ks * BK;
    load_lds16(gA0 + ko, As + wave * 16 * BK);
    load_lds16(gA1 + ko, As + (64 + wave * 16) * BK);
    load_lds16(gB0 + ko, Bs + wave * 16 * BK);
    load_lds16(gB1 + ko, Bs + (64 + wave * 16) * BK);
  };
  auto compute = [&](int s) {
    const bf16* As = (const bf16*)(smem + s * 16384);
    const bf16* Bs = As + 4096;
    bf16x8 af[4], bfr[4];
#pragma unroll
    for (int i = 0; i < 4; i++) af[i] = *(const bf16x8*)&As[offA[i]];
#pragma unroll
    for (int j = 0; j < 4; j++) bfr[j] = *(const bf16x8*)&Bs[offB[j]];
#pragma unroll
    for (int i = 0; i < 4; i++)
#pragma unroll
      for (int j = 0; j < 4; j++) acc[i][j] = MFMA16(af[i], bfr[j], acc[i][j]);
  };

  constexpr int NK = D_ / BK;  // 32
  stage(0, 0);
  __syncthreads();  // slot 0 staged
  for (int k = 0; k < NK; k += 2) {
    if (k + 1 < NK) stage(k + 1, 1);  // in flight during compute(0)
    compute(0);
    __syncthreads();  // drains k+1 loads; slot-0 reads done
    if (k + 2 < NK) stage(k + 2, 0);
    compute(1);
    __syncthreads();
  }

  // ---- coalesced epilogue through LDS ----
  const int lr = (wave & 1) * 16 + quad * 4;
  const int rrow = tid >> 3;
  const int rseg = (tid & 7) * 16;
  const int grow = bm + (rrow >> 4) * 64 + (rrow & 15);
#pragma unroll
  for (int i = 0; i < 4; i++) {
    __syncthreads();
#pragma unroll
    for (int j = 0; j < 4; j++) {
      const int col = wn + j * 16 + l16;
#pragma unroll
      for (int r = 0; r < 4; r++) {
        float x = acc[i][j][r];
        if (act) x = x > 0.f ? x + 1.f : __expf(x);
        Cl[(lr + r) * CLD + col] = x;
      }
    }
    __syncthreads();
    const float* src = &Cl[rrow * CLD + rseg];
    if (of) {
      float* dst = of + (size_t)(grow + i * 16) * D_ + colg + rseg;
#pragma unroll
      for (int u = 0; u < 4; u++)
        *(float4*)(dst + u * 4) = *(const float4*)(src + u * 4);
    } else {
      bf16x8 q0, q1;
#pragma unroll
      for (int u = 0; u < 8; u++) { q0[u] = (bf16)src[u]; q1[u] = (bf16)src[8 + u]; }
      bf16* dst = ob + (size_t)(grow + i * 16) * D_ + colg + rseg;
      *(bf16x8*)dst = q0;
      *(bf16x8*)(dst + 8) = q1;
    }
  }
}

// ---------------------------------------------------------------------------
// Pass 1: per-chunk KV outer-product sums (bf16 out) + k-sums (fp32), MFMA.
// KT/VT staged transposed with swz72: scatter writes 8-way -> conflict-free.
// grid (NC, BH) x 256.
// ---------------------------------------------------------------------------
__global__ __launch_bounds__(256) void chunk_kv(const bf16* __restrict__ kb,
                                                const bf16* __restrict__ vb,
                                                bf16* __restrict__ csum,
                                                float* __restrict__ zbuf) {
  __shared__ __align__(16) bf16 KT[DH * 72];  // KT[d][t] (swizzled)
  __shared__ __align__(16) bf16 VT[DH * 72];  // VT[e][t] (swizzled)
  const int tid = threadIdx.x;
  const int wave = tid >> 6, lane = tid & 63;
  const int quad = lane >> 4, l16 = lane & 15;
  const int c = blockIdx.x, bh = blockIdx.y;
  const int b = bh >> 4, h = bh & 15;
  const size_t gbase = ((size_t)(b * S_ + c * CHUNK)) * D_ + h * DH;
#pragma unroll
  for (int rep = 0; rep < 2; rep++) {
    int flat = tid + rep * 256;
    int r = flat >> 3, sg = (flat & 7) * 8;  // r = t, sg = d0
    bf16x8 kk = *(const bf16x8*)(kb + gbase + (size_t)r * D_ + sg);
    bf16x8 vv = *(const bf16x8*)(vb + gbase + (size_t)r * D_ + sg);
#pragma unroll
    for (int u = 0; u < 8; u++) {
      KT[swz72(sg + u, r)] = kk[u];
      VT[swz72(sg + u, r)] = vv[u];
    }
  }
  __syncthreads();

  v4f zero = {0.f, 0.f, 0.f, 0.f};
  v4f acc[4];
#pragma unroll
  for (int j = 0; j < 4; j++) acc[j] = zero;
#pragma unroll
  for (int ks = 0; ks < 2; ks++) {
    bf16x8 ak = *(const bf16x8*)&KT[swz72(wave * 16 + l16, ks * 32 + quad * 8)];
#pragma unroll
    for (int j = 0; j < 4; j++) {
      bf16x8 bv = *(const bf16x8*)&VT[swz72(j * 16 + l16, ks * 32 + quad * 8)];
      acc[j] = MFMA16(ak, bv, acc[j]);
    }
  }
  bf16* out = csum + ((size_t)bh * NC + c) * 4096;
#pragma unroll
  for (int j = 0; j < 4; j++)
#pragma unroll
    for (int r = 0; r < 4; r++)
      out[(wave * 16 + quad * 4 + r) * 64 + (j * 16 + l16)] = (bf16)acc[j][r];

  // z[d] = sum_t K[t][d]: 4 lanes per d, 16 elems each, shfl reduce (fp32)
  {
    const int d = tid >> 2, p = tid & 3;
    bf16x8 a0 = *(const bf16x8*)&KT[swz72(d, p * 16)];
    bf16x8 a1 = *(const bf16x8*)&KT[swz72(d, p * 16 + 8)];
    float zp = 0.f;
#pragma unroll
    for (int u = 0; u < 8; u++) zp += (float)a0[u] + (float)a1[u];
    zp += __shfl_xor(zp, 1, 64);
    zp += __shfl_xor(zp, 2, 64);
    if (p == 0) zbuf[((size_t)bh * NC + c) * 64 + d] = zp;
  }
}

// ---------------------------------------------------------------------------
// Exclusive prefix over chunks + state_cache init (fp32 carry).
// S-part: read bf16 csum, write bf16 exclusive-prefix into stb.
// z-part: fp32 in place in zbuf.  grid (BH, 17) x 256.
// ---------------------------------------------------------------------------
__global__ __launch_bounds__(256) void state_prefix(const float* __restrict__ sc,
                                                    const bf16* __restrict__ csum,
                                                    float* __restrict__ zbuf,
                                                    bf16* __restrict__ stb) {
  const int bh = blockIdx.x;
  const int e = blockIdx.y * 256 + threadIdx.x;
  const float* scb = sc + (size_t)bh * (DH + 1) * DH;
  if (e < 4096) {
    float run = scb[e];
    const bf16* p = csum + (size_t)bh * NC * 4096 + e;
    bf16* q = stb + (size_t)bh * NC * 4096 + e;
#pragma unroll 1
    for (int c = 0; c < NC; c += 4) {
      float t0 = (float)p[(size_t)(c + 0) * 4096];
      float t1 = (float)p[(size_t)(c + 1) * 4096];
      float t2 = (float)p[(size_t)(c + 2) * 4096];
      float t3 = (float)p[(size_t)(c + 3) * 4096];
      q[(size_t)(c + 0) * 4096] = (bf16)run; run += t0;
      q[(size_t)(c + 1) * 4096] = (bf16)run; run += t1;
      q[(size_t)(c + 2) * 4096] = (bf16)run; run += t2;
      q[(size_t)(c + 3) * 4096] = (bf16)run; run += t3;
    }
  } else if (e < 4160) {
    const int d = e - 4096;
    float run = scb[4096 + d];
    float* p = zbuf + (size_t)bh * NC * 64 + d;
#pragma unroll 1
    for (int c = 0; c < NC; c += 4) {
      float t0 = p[(size_t)(c + 0) * 64];
      float t1 = p[(size_t)(c + 1) * 64];
      float t2 = p[(size_t)(c + 2) * 64];
      float t3 = p[(size_t)(c + 3) * 64];
      p[(size_t)(c + 0) * 64] = run; run += t0;
      p[(size_t)(c + 1) * 64] = run; run += t1;
      p[(size_t)(c + 2) * 64] = run; run += t2;
      p[(size_t)(c + 3) * 64] = run; run += t3;
    }
  }
}

// ---------------------------------------------------------------------------
// Pass 2: P = mask(Q K^T) (incl. diagonal), num = P@V + Q@S0,
// den = rowsum(P) + Q.z0, out = num/(den+eps).  grid (NC, BH) x 256 (4 waves).
// All [64][72] tiles swz72-swizzled (scatter writes conflict-free, b128 reads
// optimal, pure layout bijection => bit-identical output).  Output routed
// through Ql (dead after last MFMA) for 16B coalesced global stores.
// ---------------------------------------------------------------------------
__global__ __launch_bounds__(256) void attn_pass2(
    const bf16* __restrict__ qb, const bf16* __restrict__ kb,
    const bf16* __restrict__ vb, const float* __restrict__ zbuf,
    const bf16* __restrict__ stb, bf16* __restrict__ ao) {
  __shared__ __align__(16) bf16 Ql[CHUNK * 72];
  __shared__ __align__(16) bf16 Kl[CHUNK * 72];
  __shared__ __align__(16) bf16 VT[DH * 72];    // VT[e][j] = V[j][e]
  __shared__ __align__(16) bf16 S0T[DH * 72];   // S0T[e][d] = S0[d][e]
  __shared__ __align__(16) bf16 Pl[CHUNK * 72]; // masked P [t][j]
  __shared__ float denl[CHUNK];
  __shared__ float z0l[DH];
  const int tid = threadIdx.x;
  const int wave = tid >> 6, lane = tid & 63;
  const int quad = lane >> 4, l16 = lane & 15;
  const int c = blockIdx.x, bh = blockIdx.y;
  const int b = bh >> 4, h = bh & 15;
  const size_t gbase = ((size_t)(b * S_ + c * CHUNK)) * D_ + h * DH;

#pragma unroll
  for (int rep = 0; rep < 2; rep++) {
    int flat = tid + rep * 256;
    int r = flat >> 3, sg = (flat & 7) * 8;
    *(bf16x8*)&Ql[swz72(r, sg)] = *(const bf16x8*)(qb + gbase + (size_t)r * D_ + sg);
    *(bf16x8*)&Kl[swz72(r, sg)] = *(const bf16x8*)(kb + gbase + (size_t)r * D_ + sg);
    bf16x8 vv = *(const bf16x8*)(vb + gbase + (size_t)r * D_ + sg);
#pragma unroll
    for (int u = 0; u < 8; u++) VT[swz72(sg + u, r)] = vv[u];
  }
  // S0 staging from bf16 prefix states: thread handles 16 contiguous elems
  {
    const bf16* stb_c = stb + ((size_t)bh * NC + c) * 4096;
    const int f0 = tid * 16;
    const int col = f0 >> 6, row0 = f0 & 63;  // row0 in {0,16,32,48}
    bf16x8 a0 = *(const bf16x8*)&stb_c[f0];
    bf16x8 a1 = *(const bf16x8*)&stb_c[f0 + 8];
#pragma unroll
    for (int u = 0; u < 8; u++) {
      S0T[swz72(row0 + u, col)] = a0[u];
      S0T[swz72(row0 + 8 + u, col)] = a1[u];
    }
  }
  if (tid < DH) z0l[tid] = zbuf[((size_t)bh * NC + c) * 64 + tid];
  __syncthreads();

  // phase 1: P = Q K^T
  v4f zero = {0.f, 0.f, 0.f, 0.f};
  v4f pacc[4];
#pragma unroll
  for (int j = 0; j < 4; j++) pacc[j] = zero;
#pragma unroll
  for (int ks = 0; ks < 2; ks++) {
    bf16x8 aq = *(const bf16x8*)&Ql[swz72(wave * 16 + l16, ks * 32 + quad * 8)];
#pragma unroll
    for (int j = 0; j < 4; j++) {
      bf16x8 bk = *(const bf16x8*)&Kl[swz72(j * 16 + l16, ks * 32 + quad * 8)];
      pacc[j] = MFMA16(aq, bk, pacc[j]);
    }
  }
  float rs[4] = {0.f, 0.f, 0.f, 0.f};
#pragma unroll
  for (int j = 0; j < 4; j++) {
#pragma unroll
    for (int r = 0; r < 4; r++) {
      int t = wave * 16 + quad * 4 + r;
      int col = j * 16 + l16;
      float p = (col <= t) ? pacc[j][r] : 0.f;
      Pl[swz72(t, col)] = (bf16)p;
      rs[r] += p;
    }
  }
#pragma unroll
  for (int m = 1; m < 16; m <<= 1)
#pragma unroll
    for (int r = 0; r < 4; r++) rs[r] += __shfl_xor(rs[r], m, 64);
  if (l16 == 0)
#pragma unroll
    for (int r = 0; r < 4; r++) denl[wave * 16 + quad * 4 + r] = rs[r];
  __syncthreads();
  // den += q . z0 (wave-parallel: t = tid>>2 covers 0..63, p = 16-elem slice)
  {
    const int t = tid >> 2, p = tid & 3;
    bf16x8 qa = *(const bf16x8*)&Ql[swz72(t, p * 16)];
    bf16x8 qb2 = *(const bf16x8*)&Ql[swz72(t, p * 16 + 8)];
    float qz = 0.f;
#pragma unroll
    for (int u = 0; u < 8; u++)
      qz += (float)qa[u] * z0l[p * 16 + u] + (float)qb2[u] * z0l[p * 16 + 8 + u];
    qz += __shfl_xor(qz, 1, 64);
    qz += __shfl_xor(qz, 2, 64);
    if (p == 0) denl[t] += qz;
  }
  __syncthreads();

  // phase 2: num = P@V + Q@S0
  v4f nacc[4];
#pragma unroll
  for (int j = 0; j < 4; j++) nacc[j] = zero;
#pragma unroll
  for (int ks = 0; ks < 2; ks++) {
    bf16x8 ap = *(const bf16x8*)&Pl[swz72(wave * 16 + l16, ks * 32 + quad * 8)];
#pragma unroll
    for (int j = 0; j < 4; j++) {
      bf16x8 bv = *(const bf16x8*)&VT[swz72(j * 16 + l16, ks * 32 + quad * 8)];
      nacc[j] = MFMA16(ap, bv, nacc[j]);
    }
  }
#pragma unroll
  for (int ks = 0; ks < 2; ks++) {
    bf16x8 aq = *(const bf16x8*)&Ql[swz72(wave * 16 + l16, ks * 32 + quad * 8)];
#pragma unroll
    for (int j = 0; j < 4; j++) {
      bf16x8 bs = *(const bf16x8*)&S0T[swz72(j * 16 + l16, ks * 32 + quad * 8)];
      nacc[j] = MFMA16(aq, bs, nacc[j]);
    }
  }

  // epilogue: route output through Ql (dead now) for coalesced 16B stores
  __syncthreads();  // all waves done reading Ql/VT/S0T/Pl
  bf16* Ol = Ql;
#pragma unroll
  for (int j = 0; j < 4; j++) {
#pragma unroll
    for (int r = 0; r < 4; r++) {
      int t = wave * 16 + quad * 4 + r;
      int e = j * 16 + l16;
      Ol[swz72(t, e)] = (bf16)(nacc[j][r] / (denl[t] + EPS));
    }
  }
  __syncthreads();
  {
    const int orow = tid >> 2, oc0 = (tid & 3) * 16;
    bf16x8 q0 = *(const bf16x8*)&Ol[swz72(orow, oc0)];
    bf16x8 q1 = *(const bf16x8*)&Ol[swz72(orow, oc0 + 8)];
    bf16* dst = ao + gbase + (size_t)orow * D_ + oc0;
    *(bf16x8*)dst = q0;
    *(bf16x8*)(dst + 8) = q1;
  }
}

// ---------------------------------------------------------------------------
extern "C" void kernel_launch(void* const* d_in, const int* in_sizes, int n_in,
                              void* d_out, int out_size, void* d_ws, size_t ws_size,
                              hipStream_t stream) {
  const float* x  = (const float*)d_in[0];
  const float* sc = (const float*)d_in[1];
  const float* Wq = (const float*)d_in[2];
  const float* Wk = (const float*)d_in[3];
  const float* Wv = (const float*)d_in[4];
  const float* Wo = (const float*)d_in[5];
  float* out = (float*)d_out;

  const size_t MSZ = (size_t)B_ * S_ * D_;  // 16,777,216 elems
  const size_t WSZ = (size_t)D_ * D_;       // 1,048,576 elems
  bf16* xb = (bf16*)d_ws;
  bf16* qb = xb + MSZ;
  bf16* kb = qb + MSZ;
  bf16* vb = kb + MSZ;
  bf16* ao = vb + MSZ;
  bf16* wt = ao + MSZ;  // 4 transposed bf16 weight matrices [q|k|v|o]
  bf16* csum = wt + 4 * WSZ;            // bf16 chunk sums: BH*NC*4096 (32 MB)
  float* zbuf = (float*)(csum + (size_t)BH * NC * 4096);  // fp32 z: 1 MB
  bf16* stb = xb;  // bf16 prefix states reuse xb (dead after QKV GEMM);
                   // BH*NC*4096 = 16,777,216 elems — exact fit.

  cvt_f32_bf16<<<MSZ / (256 * 8), 256, 0, stream>>>(x, xb);
  transpose_w4<<<dim3(32, 32, 4), 256, 0, stream>>>(Wq, Wk, Wv, Wo, wt);

  // fused QKV GEMM: BT rows 0..3071 span wt[q|k|v]
  gemm_nt<<<dim3(128, 24), 256, 0, stream>>>(xb, wt, qb, kb, vb, nullptr);

  chunk_kv<<<dim3(NC, BH), 256, 0, stream>>>(kb, vb, csum, zbuf);
  state_prefix<<<dim3(BH, 17), 256, 0, stream>>>(sc, csum, zbuf, stb);
  attn_pass2<<<dim3(NC, BH), 256, 0, stream>>>(qb, kb, vb, zbuf, stb, ao);

  gemm_nt<<<dim3(128, 8), 256, 0, stream>>>(ao, wt + 3 * WSZ, nullptr, nullptr,
                                            nullptr, out);
}